// Round 1
// baseline (253.722 us; speedup 1.0000x reference)
//
#include <hip/hip_runtime.h>
#include <hip/hip_fp16.h>

// DCNv2: B=2, CIN=COUT=64, H=W=128, DG=8, cpg=8, 3x3 s1 p1 d1
constexpr int BB = 2;
constexpr int CINc = 64;
constexpr int HWc = 128 * 128;
constexpr int DGc = 8;
constexpr int OCOFFc = 216;   // DG*3*9 offset-conv channels
// workspace layout (bytes)
constexpr size_t OFFS_BYTES = (size_t)BB * OCOFFc * HWc * 2;   // fp16 offsets+masks
constexpr size_t XT_OFF     = OFFS_BYTES;
constexpr size_t XT_BYTES   = (size_t)BB * DGc * HWc * 8 * 2;  // x transposed [b][dg][y][x][8c] fp16
constexpr size_t WT1_OFF    = XT_OFF + XT_BYTES;
constexpr size_t WT1_BYTES  = (size_t)576 * 256 * 4;           // offset-conv W, k-major, oc padded to 256, fp32
constexpr size_t WT2_OFF    = WT1_OFF + WT1_BYTES;
constexpr size_t WT2_BYTES  = (size_t)DGc * 72 * 64 * 2;       // main W [dg][kl=c*9+k][oc] fp16
constexpr size_t WS_NEEDED  = WT2_OFF + WT2_BYTES;             // ~19.0 MB

// ---------- K0a: x -> xT[b][dg][y][x][8ch] fp16 (channel-vectorized gathers) ----------
__global__ void prep_xt(const float* __restrict__ x, __half* __restrict__ xT) {
    int site = blockIdx.x * 256 + threadIdx.x;      // B*DG*HW = 262144
    int pix = site & (HWc - 1);
    int bdg = site >> 14;
    int dg = bdg & 7, b = bdg >> 3;
    const float* xp = x + (size_t)(b * CINc + dg * 8) * HWc + pix;
    __half2 h0 = __halves2half2(__float2half(xp[0 * HWc]), __float2half(xp[1 * HWc]));
    __half2 h1 = __halves2half2(__float2half(xp[2 * HWc]), __float2half(xp[3 * HWc]));
    __half2 h2 = __halves2half2(__float2half(xp[4 * HWc]), __float2half(xp[5 * HWc]));
    __half2 h3 = __halves2half2(__float2half(xp[6 * HWc]), __float2half(xp[7 * HWc]));
    __half2* o = reinterpret_cast<__half2*>(xT + (size_t)site * 8);
    o[0] = h0; o[1] = h1; o[2] = h2; o[3] = h3;     // merges to dwordx4
}

// ---------- K0b: weight layout transforms (one-time, small) ----------
__global__ void prep_w(const float* __restrict__ w_off, const float* __restrict__ weight,
                       float* __restrict__ wT1, __half* __restrict__ wT2) {
    int idx = blockIdx.x * 256 + threadIdx.x;
    if (idx < 576 * 256) {                // wT1[k][oc_pad256]
        int k = idx >> 8, oc = idx & 255;
        wT1[idx] = (oc < OCOFFc) ? w_off[oc * 576 + k] : 0.f;
    } else {
        int j = idx - 576 * 256;          // wT2[dg][kl][oc], kl = c*9+k
        if (j < DGc * 72 * 64) {
            int oc = j & 63;
            int kl = (j >> 6) % 72;
            int dg = j / (64 * 72);
            wT2[j] = __float2half(weight[oc * 576 + dg * 72 + kl]);
        }
    }
}

// ---------- K1: 216-ch offset conv (implicit GEMM, fp32), sigmoid on mask, fp16 out ----------
__global__ __launch_bounds__(256, 2) void offset_conv_k(
        const float* __restrict__ x, const float* __restrict__ wT1,
        const float* __restrict__ cob, __half* __restrict__ offs) {
    __shared__ float xs[64 * 120];    // [cin][10 rows][12 pad]
    __shared__ float wch[64 * 132];   // [kl][128 oc, pad 132 -> 16B aligned rows]
    const int tid = threadIdx.x;
    const int tx = blockIdx.x, ty = blockIdx.y, b = blockIdx.z;

    for (int idx = tid; idx < 6400; idx += 256) {
        int c = idx / 100;
        int rem = idx - c * 100;
        int r = rem / 10;
        int s = rem - r * 10;
        int gy = ty * 8 - 1 + r, gx = tx * 8 - 1 + s;
        float v = 0.f;
        if ((unsigned)gy < 128u && (unsigned)gx < 128u)
            v = x[(size_t)(b * CINc + c) * HWc + gy * 128 + gx];
        xs[c * 120 + r * 12 + s] = v;
    }

    const int pxq = tid & 15;          // 16 pixel-quads (4 consecutive px each)
    const int ocg = tid >> 4;          // 16 oc-groups of 8
    const int xoff = (pxq >> 1) * 12 + (pxq & 1) * 4;
    const int gy = ty * 8 + (pxq >> 1);
    const int gx0 = tx * 8 + (pxq & 1) * 4;

    for (int pass = 0; pass < 2; ++pass) {
        const int ocbase = pass * 128;
        float acc[4][8];
        #pragma unroll
        for (int p = 0; p < 4; ++p)
            #pragma unroll
            for (int j = 0; j < 8; ++j) acc[p][j] = 0.f;

        for (int kc = 0; kc < 9; ++kc) {
            __syncthreads();
            #pragma unroll
            for (int i = 0; i < 32; ++i) {       // 64k x 128oc chunk, both sides coalesced
                int idx = tid + i * 256;
                int kl = idx >> 7, ol = idx & 127;
                wch[kl * 132 + ol] = wT1[(kc * 64 + kl) * 256 + ocbase + ol];
            }
            __syncthreads();
            #pragma unroll 8
            for (int kl = 0; kl < 64; ++kl) {
                int k = kc * 64 + kl;            // uniform -> SALU
                int cin = k / 9;
                int rs = k - cin * 9;
                int r = rs / 3;
                int s = rs - r * 3;
                const float* xrow = &xs[cin * 120 + r * 12 + s + xoff];
                float xv0 = xrow[0], xv1 = xrow[1], xv2 = xrow[2], xv3 = xrow[3];
                const float* wrow = &wch[kl * 132 + ocg * 8];   // 2x ds_read_b128, broadcast
                #pragma unroll
                for (int j = 0; j < 8; ++j) {
                    float wv = wrow[j];
                    acc[0][j] += xv0 * wv;
                    acc[1][j] += xv1 * wv;
                    acc[2][j] += xv2 * wv;
                    acc[3][j] += xv3 * wv;
                }
            }
        }
        #pragma unroll
        for (int j = 0; j < 8; ++j) {
            int oc = ocbase + ocg * 8 + j;
            if (oc < OCOFFc) {
                float bi = cob[oc];
                __half hv[4];
                #pragma unroll
                for (int p = 0; p < 4; ++p) {
                    float v = acc[p][j] + bi;
                    if (oc >= 144) v = 1.f / (1.f + __expf(-v));   // sigmoid(mask)
                    hv[p] = __float2half(v);
                }
                __half* dst = offs + (size_t)(b * OCOFFc + oc) * HWc + gy * 128 + gx0;
                reinterpret_cast<__half2*>(dst)[0] = __halves2half2(hv[0], hv[1]);
                reinterpret_cast<__half2*>(dst)[1] = __halves2half2(hv[2], hv[3]);
            }
        }
    }
}

// ---------- K2: bilinear sampling + main conv (per-dg col staging + register GEMM) ----------
__global__ __launch_bounds__(256, 4) void dcn_main_k(
        const __half* __restrict__ offs, const __half* __restrict__ xT,
        const __half* __restrict__ wT2, const float* __restrict__ bias,
        float* __restrict__ out) {
    __shared__ __align__(16) __half colbuf[72 * 64];   // [kl=c*9+k][px]
    __shared__ __align__(16) __half wc2[72 * 64];      // [kl][oc]
    const int tid = threadIdx.x;
    const int tx = blockIdx.x, ty = blockIdx.y, b = blockIdx.z;
    const int pxq = tid & 15;
    const int ocg = tid >> 4;
    const int px0 = pxq * 4;

    float acc[4][4];
    #pragma unroll
    for (int p = 0; p < 4; ++p)
        #pragma unroll
        for (int q = 0; q < 4; ++q) acc[p][q] = 0.f;

    #pragma unroll 1
    for (int dg = 0; dg < 8; ++dg) {
        __syncthreads();
        for (int idx = tid; idx < 4608; idx += 256)
            wc2[idx] = wT2[dg * 4608 + idx];

        for (int j = tid; j < 576; j += 256) {          // 9 taps x 64 px; k uniform per wave
            const int px = j & 63;
            const int k = j >> 6;
            const int gyj = ty * 8 + (px >> 3), gxj = tx * 8 + (px & 7);
            const int pix = gyj * 128 + gxj;
            const int dgk = dg * 9 + k;
            float oy = __half2float(offs[(size_t)(b * 216 + dgk * 2) * HWc + pix]);
            float ox = __half2float(offs[(size_t)(b * 216 + dgk * 2 + 1) * HWc + pix]);
            float m  = __half2float(offs[(size_t)(b * 216 + 144 + dgk) * HWc + pix]);
            const int ki = k / 3, kj = k - ki * 3;
            float sy = oy + (float)(gyj - 1 + ki);
            float sx = ox + (float)(gxj - 1 + kj);
            float y0f = floorf(sy), x0f = floorf(sx);
            int iy0 = (int)y0f, ix0 = (int)x0f;
            float ly = sy - y0f, lx = sx - x0f;
            float hy = 1.f - ly, hx = 1.f - lx;
            float vy0 = ((unsigned)iy0 < 128u) ? 1.f : 0.f;
            float vy1 = ((unsigned)(iy0 + 1) < 128u) ? 1.f : 0.f;
            float vx0 = ((unsigned)ix0 < 128u) ? 1.f : 0.f;
            float vx1 = ((unsigned)(ix0 + 1) < 128u) ? 1.f : 0.f;
            float w00 = hy * hx * vy0 * vx0, w01 = hy * lx * vy0 * vx1;
            float w10 = ly * hx * vy1 * vx0, w11 = ly * lx * vy1 * vx1;
            int y0c = min(max(iy0, 0), 127), y1c = min(max(iy0 + 1, 0), 127);
            int x0c = min(max(ix0, 0), 127), x1c = min(max(ix0 + 1, 0), 127);
            const __half* xbase = xT + (size_t)(b * 8 + dg) * HWc * 8;
            float4 f00 = *reinterpret_cast<const float4*>(xbase + (y0c * 128 + x0c) * 8);
            float4 f01 = *reinterpret_cast<const float4*>(xbase + (y0c * 128 + x1c) * 8);
            float4 f10 = *reinterpret_cast<const float4*>(xbase + (y1c * 128 + x0c) * 8);
            float4 f11 = *reinterpret_cast<const float4*>(xbase + (y1c * 128 + x1c) * 8);
            const __half2* a00 = reinterpret_cast<const __half2*>(&f00);
            const __half2* a01 = reinterpret_cast<const __half2*>(&f01);
            const __half2* a10 = reinterpret_cast<const __half2*>(&f10);
            const __half2* a11 = reinterpret_cast<const __half2*>(&f11);
            #pragma unroll
            for (int cc = 0; cc < 4; ++cc) {
                float2 v00 = __half22float2(a00[cc]);
                float2 v01 = __half22float2(a01[cc]);
                float2 v10 = __half22float2(a10[cc]);
                float2 v11 = __half22float2(a11[cc]);
                float c0 = m * (w00 * v00.x + w01 * v01.x + w10 * v10.x + w11 * v11.x);
                float c1 = m * (w00 * v00.y + w01 * v01.y + w10 * v10.y + w11 * v11.y);
                colbuf[(cc * 18 + k) * 64 + px] = __float2half(c0);
                colbuf[(cc * 18 + 9 + k) * 64 + px] = __float2half(c1);
            }
        }
        __syncthreads();

        #pragma unroll 2
        for (int kl = 0; kl < 72; ++kl) {
            const __half2* cp = reinterpret_cast<const __half2*>(&colbuf[kl * 64 + px0]);
            float2 c01 = __half22float2(cp[0]);
            float2 c23 = __half22float2(cp[1]);
            const __half2* wp = reinterpret_cast<const __half2*>(&wc2[kl * 64 + ocg * 4]);
            float2 w01v = __half22float2(wp[0]);
            float2 w23v = __half22float2(wp[1]);
            float cv[4] = {c01.x, c01.y, c23.x, c23.y};
            float wv[4] = {w01v.x, w01v.y, w23v.x, w23v.y};
            #pragma unroll
            for (int p = 0; p < 4; ++p)
                #pragma unroll
                for (int q = 0; q < 4; ++q) acc[p][q] += cv[p] * wv[q];
        }
    }

    const int gys = ty * 8 + (pxq >> 1);
    const int gx0s = tx * 8 + (pxq & 1) * 4;
    #pragma unroll
    for (int q = 0; q < 4; ++q) {
        int oc = ocg * 4 + q;
        float bi = bias[oc];
        float4 v = make_float4(acc[0][q] + bi, acc[1][q] + bi, acc[2][q] + bi, acc[3][q] + bi);
        *reinterpret_cast<float4*>(out + (size_t)(b * 64 + oc) * HWc + gys * 128 + gx0s) = v;
    }
}

extern "C" void kernel_launch(void* const* d_in, const int* in_sizes, int n_in,
                              void* d_out, int out_size, void* d_ws, size_t ws_size,
                              hipStream_t stream) {
    const float* x      = (const float*)d_in[0];
    const float* w_off  = (const float*)d_in[1];
    const float* cob    = (const float*)d_in[2];
    const float* weight = (const float*)d_in[3];
    const float* bias   = (const float*)d_in[4];
    float* out = (float*)d_out;
    if (ws_size < WS_NEEDED) return;   // loud failure signal if ws too small

    char* ws = (char*)d_ws;
    __half* offs = (__half*)ws;
    __half* xT   = (__half*)(ws + XT_OFF);
    float*  wT1  = (float*)(ws + WT1_OFF);
    __half* wT2  = (__half*)(ws + WT2_OFF);

    prep_xt<<<1024, 256, 0, stream>>>(x, xT);
    prep_w<<<720, 256, 0, stream>>>(w_off, weight, wT1, wT2);
    offset_conv_k<<<dim3(16, 16, 2), 256, 0, stream>>>(x, wT1, cob, offs);
    dcn_main_k<<<dim3(16, 16, 2), 256, 0, stream>>>(offs, xT, wT2, bias, out);
}

// Round 2
// 129.671 us; speedup vs baseline: 1.9567x; 1.9567x over previous
//
#include <hip/hip_runtime.h>
#include <hip/hip_fp16.h>

// DCNv2: B=2, CIN=COUT=64, H=W=128, DG=8, cpg=8, 3x3 s1 p1 d1
constexpr int BB = 2;
constexpr int CINc = 64;
constexpr int HWc = 128 * 128;
constexpr int OCOFFc = 216;   // DG*3*9 offset-conv channels
constexpr int XP = 130;       // padded spatial dim (halo of 1)

// workspace layout (bytes)
constexpr size_t OFFS_BYTES = (size_t)BB * OCOFFc * HWc * 2;        // fp16 offsets+masks
constexpr size_t XTFP_OFF   = OFFS_BYTES;
constexpr size_t XTFP_BYTES = (size_t)BB * XP * XP * 64 * 2;        // padded swizzled x fp16
constexpr size_t WB1_OFF    = XTFP_OFF + XTFP_BYTES;
constexpr size_t WB1_BYTES  = (size_t)9 * 256 * 64 * 2;             // offset W [tap][oc256][slot][8] fp16 swizzled
constexpr size_t WT2_OFF    = WB1_OFF + WB1_BYTES;
constexpr size_t WT2_BYTES  = (size_t)8 * 72 * 64 * 2;              // main W [dg][kl][oc] fp16
constexpr size_t WS_NEEDED  = WT2_OFF + WT2_BYTES;                  // ~18.9 MB

typedef _Float16 f16x8 __attribute__((ext_vector_type(8)));
typedef float    f32x4 __attribute__((ext_vector_type(4)));

// ---------- K0a: x -> padded swizzled fp16 [b][y+1][x+1][slot=dg^((x+1)&7)][8ch] ----------
__global__ void prep_xt(const float* __restrict__ x, __half* __restrict__ xTfP) {
    int site = blockIdx.x * 256 + threadIdx.x;      // B*8*HW = 262144
    int pix = site & (HWc - 1);
    int bdg = site >> 14;
    int dg = bdg & 7, b = bdg >> 3;
    int y = pix >> 7, xc = pix & 127;
    const float* xp = x + (size_t)(b * CINc + dg * 8) * HWc + pix;
    __half2 h0 = __halves2half2(__float2half(xp[0 * HWc]), __float2half(xp[1 * HWc]));
    __half2 h1 = __halves2half2(__float2half(xp[2 * HWc]), __float2half(xp[3 * HWc]));
    __half2 h2 = __halves2half2(__float2half(xp[4 * HWc]), __float2half(xp[5 * HWc]));
    __half2 h3 = __halves2half2(__float2half(xp[6 * HWc]), __float2half(xp[7 * HWc]));
    int slot = dg ^ ((xc + 1) & 7);
    __half2* o = reinterpret_cast<__half2*>(
        xTfP + (((size_t)b * XP + y + 1) * XP + xc + 1) * 64 + slot * 8);
    o[0] = h0; o[1] = h1; o[2] = h2; o[3] = h3;
}

// ---------- K0b: weight layout transforms ----------
__global__ void prep_w(const float* __restrict__ w_off, const float* __restrict__ weight,
                       __half* __restrict__ wB1, __half* __restrict__ wT2) {
    int idx = blockIdx.x * 256 + threadIdx.x;
    if (idx < 9 * 256 * 64) {
        // wB1[tap][oc][sl][ci], slot sl holds cin-group sl^(oc&7)
        int ci = idx & 7;
        int sl = (idx >> 3) & 7;
        int oc = (idx >> 6) & 255;
        int tap = idx >> 14;
        int cin = ((sl ^ (oc & 7)) << 3) + ci;
        float v = (oc < OCOFFc) ? w_off[oc * 576 + cin * 9 + tap] : 0.f;
        wB1[idx] = __float2half(v);
    } else {
        int j = idx - 9 * 256 * 64;          // wT2[dg][kl][oc], kl = c*9+k
        if (j < 8 * 72 * 64) {
            int oc = j & 63;
            int kl = (j >> 6) % 72;
            int dg = j / (64 * 72);
            wT2[j] = __float2half(weight[oc * 576 + dg * 72 + kl]);
        }
    }
}

// ---------- K1: offset conv as implicit-GEMM MFMA (fp16 in, fp32 acc) ----------
// block: 512 thr = 8 waves (2 px-halves x 4 oc-quarters); tile 128px(16x8) x 256oc
__global__ __launch_bounds__(512, 1) void offset_mfma_k(
        const __half* __restrict__ xTfP, const __half* __restrict__ wB1,
        const float* __restrict__ cob, __half* __restrict__ offs) {
    __shared__ __half xs[1440 * 8];    // 23040 B: [10 rows][18 cols][8 slots][8ch]
    __shared__ __half wsh[2048 * 8];   // 32768 B: [256 oc][8 slots][8ch]
    const int tid = threadIdx.x;
    const int bx = blockIdx.x;         // 0..7   (16 px wide)
    const int by = blockIdx.y;         // 0..15  (8 px tall)
    const int b  = blockIdx.z;

    // stage x patch: rows by*8+0..9, cols bx*16+0..17 of padded tensor (linear copy)
    const __half* xg = xTfP + (size_t)b * XP * XP * 64;
    #pragma unroll
    for (int it = 0; it < 3; ++it) {
        int idx = tid + it * 512;
        if (idx < 1440) {
            int yl = idx / 144;                  // 144 = 18 cols * 8 slots
            int rem = idx - yl * 144;
            float4 v = *reinterpret_cast<const float4*>(
                xg + ((size_t)(by * 8 + yl) * XP + bx * 16) * 64 + rem * 8);
            *reinterpret_cast<float4*>(xs + idx * 8) = v;
        }
    }

    const int lane = tid & 63;
    const int wid = tid >> 6;
    const int wr = wid & 1;            // px half (4 rows each)
    const int wc = wid >> 1;           // oc quarter (64 oc each)
    const int l15 = lane & 15, lh = lane >> 4;

    f32x4 acc[4][4];
    const f32x4 zero = {0.f, 0.f, 0.f, 0.f};
    #pragma unroll
    for (int ty = 0; ty < 4; ++ty)
        #pragma unroll
        for (int ot = 0; ot < 4; ++ot) acc[ty][ot] = zero;

    // prefetch tap 0 weights
    float4 wreg[4];
    #pragma unroll
    for (int i = 0; i < 4; ++i)
        wreg[i] = *reinterpret_cast<const float4*>(wB1 + (size_t)(tid + i * 512) * 8);
    __syncthreads();   // xs ready

    for (int tap = 0; tap < 9; ++tap) {
        #pragma unroll
        for (int i = 0; i < 4; ++i)
            *reinterpret_cast<float4*>(wsh + (size_t)(tid + i * 512) * 8) = wreg[i];
        __syncthreads();   // wsh ready
        if (tap < 8) {
            #pragma unroll
            for (int i = 0; i < 4; ++i)
                wreg[i] = *reinterpret_cast<const float4*>(
                    wB1 + (size_t)(tap + 1) * 16384 + (size_t)(tid + i * 512) * 8);
        }
        const int r = tap / 3, s = tap - r * 3;
        const int j = l15 + s;                    // patch col
        #pragma unroll
        for (int h = 0; h < 2; ++h) {
            const int c = h * 4 + lh;             // cin group 0..7
            const int sl = c ^ (j & 7);
            f16x8 af[4], bf[4];
            #pragma unroll
            for (int ty = 0; ty < 4; ++ty) {
                int row = wr * 4 + ty + r;
                af[ty] = *reinterpret_cast<const f16x8*>(xs + (row * 18 + j) * 64 + sl * 8);
            }
            #pragma unroll
            for (int ot = 0; ot < 4; ++ot) {
                int oc = wc * 64 + ot * 16 + l15;
                int slw = c ^ (oc & 7);
                bf[ot] = *reinterpret_cast<const f16x8*>(wsh + oc * 64 + slw * 8);
            }
            #pragma unroll
            for (int ty = 0; ty < 4; ++ty)
                #pragma unroll
                for (int ot = 0; ot < 4; ++ot)
                    acc[ty][ot] = __builtin_amdgcn_mfma_f32_16x16x32_f16(
                        af[ty], bf[ot], acc[ty][ot], 0, 0, 0);
        }
        __syncthreads();   // protect wsh before next overwrite
    }

    // epilogue: D[px=4*lh+reg][oc=l15] per tile
    #pragma unroll
    for (int ot = 0; ot < 4; ++ot) {
        int oc = wc * 64 + ot * 16 + l15;
        if (oc >= OCOFFc) continue;
        float bi = cob[oc];
        bool sig = (oc >= 144);
        #pragma unroll
        for (int ty = 0; ty < 4; ++ty) {
            int gy = by * 8 + wr * 4 + ty;
            int gx = bx * 16 + lh * 4;
            float v0 = acc[ty][ot][0] + bi, v1 = acc[ty][ot][1] + bi;
            float v2 = acc[ty][ot][2] + bi, v3 = acc[ty][ot][3] + bi;
            if (sig) {
                v0 = 1.f / (1.f + __expf(-v0)); v1 = 1.f / (1.f + __expf(-v1));
                v2 = 1.f / (1.f + __expf(-v2)); v3 = 1.f / (1.f + __expf(-v3));
            }
            __half* dst = offs + (size_t)(b * OCOFFc + oc) * HWc + gy * 128 + gx;
            reinterpret_cast<__half2*>(dst)[0] = __halves2half2(__float2half(v0), __float2half(v1));
            reinterpret_cast<__half2*>(dst)[1] = __halves2half2(__float2half(v2), __float2half(v3));
        }
    }
}

// ---------- K2: bilinear sampling + main conv (per-dg col staging + register GEMM) ----------
__global__ __launch_bounds__(256, 4) void dcn_main_k(
        const __half* __restrict__ offs, const __half* __restrict__ xTfP,
        const __half* __restrict__ wT2, const float* __restrict__ bias,
        float* __restrict__ out) {
    __shared__ __align__(16) __half colbuf[72 * 64];   // [kl=c*9+k][px]
    __shared__ __align__(16) __half wc2[72 * 64];      // [kl][oc]
    const int tid = threadIdx.x;
    const int tx = blockIdx.x, ty = blockIdx.y, b = blockIdx.z;
    const int pxq = tid & 15;
    const int ocg = tid >> 4;
    const int px0 = pxq * 4;

    float acc[4][4];
    #pragma unroll
    for (int p = 0; p < 4; ++p)
        #pragma unroll
        for (int q = 0; q < 4; ++q) acc[p][q] = 0.f;

    #pragma unroll 1
    for (int dg = 0; dg < 8; ++dg) {
        __syncthreads();
        for (int idx = tid; idx < 4608; idx += 256)
            wc2[idx] = wT2[dg * 4608 + idx];

        for (int j = tid; j < 576; j += 256) {          // 9 taps x 64 px
            const int px = j & 63;
            const int k = j >> 6;
            const int gyj = ty * 8 + (px >> 3), gxj = tx * 8 + (px & 7);
            const int pix = gyj * 128 + gxj;
            const int dgk = dg * 9 + k;
            float oy = __half2float(offs[(size_t)(b * 216 + dgk * 2) * HWc + pix]);
            float ox = __half2float(offs[(size_t)(b * 216 + dgk * 2 + 1) * HWc + pix]);
            float m  = __half2float(offs[(size_t)(b * 216 + 144 + dgk) * HWc + pix]);
            const int ki = k / 3, kj = k - ki * 3;
            float sy = oy + (float)(gyj - 1 + ki);
            float sx = ox + (float)(gxj - 1 + kj);
            float y0f = floorf(sy), x0f = floorf(sx);
            int iy0 = (int)y0f, ix0 = (int)x0f;
            float ly = sy - y0f, lx = sx - x0f;
            float hy = 1.f - ly, hx = 1.f - lx;
            float vy0 = ((unsigned)iy0 < 128u) ? 1.f : 0.f;
            float vy1 = ((unsigned)(iy0 + 1) < 128u) ? 1.f : 0.f;
            float vx0 = ((unsigned)ix0 < 128u) ? 1.f : 0.f;
            float vx1 = ((unsigned)(ix0 + 1) < 128u) ? 1.f : 0.f;
            float w00 = hy * hx * vy0 * vx0, w01 = hy * lx * vy0 * vx1;
            float w10 = ly * hx * vy1 * vx0, w11 = ly * lx * vy1 * vx1;
            int y0c = min(max(iy0, 0), 127), y1c = min(max(iy0 + 1, 0), 127);
            int x0c = min(max(ix0, 0), 127), x1c = min(max(ix0 + 1, 0), 127);
            const __half* xb = xTfP + (size_t)b * XP * XP * 64;
            float4 f00 = *reinterpret_cast<const float4*>(
                xb + ((size_t)(y0c + 1) * XP + x0c + 1) * 64 + ((dg ^ ((x0c + 1) & 7)) << 3));
            float4 f01 = *reinterpret_cast<const float4*>(
                xb + ((size_t)(y0c + 1) * XP + x1c + 1) * 64 + ((dg ^ ((x1c + 1) & 7)) << 3));
            float4 f10 = *reinterpret_cast<const float4*>(
                xb + ((size_t)(y1c + 1) * XP + x0c + 1) * 64 + ((dg ^ ((x0c + 1) & 7)) << 3));
            float4 f11 = *reinterpret_cast<const float4*>(
                xb + ((size_t)(y1c + 1) * XP + x1c + 1) * 64 + ((dg ^ ((x1c + 1) & 7)) << 3));
            const __half2* a00 = reinterpret_cast<const __half2*>(&f00);
            const __half2* a01 = reinterpret_cast<const __half2*>(&f01);
            const __half2* a10 = reinterpret_cast<const __half2*>(&f10);
            const __half2* a11 = reinterpret_cast<const __half2*>(&f11);
            #pragma unroll
            for (int cc = 0; cc < 4; ++cc) {
                float2 v00 = __half22float2(a00[cc]);
                float2 v01 = __half22float2(a01[cc]);
                float2 v10 = __half22float2(a10[cc]);
                float2 v11 = __half22float2(a11[cc]);
                float c0 = m * (w00 * v00.x + w01 * v01.x + w10 * v10.x + w11 * v11.x);
                float c1 = m * (w00 * v00.y + w01 * v01.y + w10 * v10.y + w11 * v11.y);
                colbuf[(cc * 18 + k) * 64 + px] = __float2half(c0);
                colbuf[(cc * 18 + 9 + k) * 64 + px] = __float2half(c1);
            }
        }
        __syncthreads();

        #pragma unroll 2
        for (int kl = 0; kl < 72; ++kl) {
            const __half2* cp = reinterpret_cast<const __half2*>(&colbuf[kl * 64 + px0]);
            float2 c01 = __half22float2(cp[0]);
            float2 c23 = __half22float2(cp[1]);
            const __half2* wp = reinterpret_cast<const __half2*>(&wc2[kl * 64 + ocg * 4]);
            float2 w01v = __half22float2(wp[0]);
            float2 w23v = __half22float2(wp[1]);
            float cv[4] = {c01.x, c01.y, c23.x, c23.y};
            float wv[4] = {w01v.x, w01v.y, w23v.x, w23v.y};
            #pragma unroll
            for (int p = 0; p < 4; ++p)
                #pragma unroll
                for (int q = 0; q < 4; ++q) acc[p][q] += cv[p] * wv[q];
        }
    }

    const int gys = ty * 8 + (pxq >> 1);
    const int gx0s = tx * 8 + (pxq & 1) * 4;
    #pragma unroll
    for (int q = 0; q < 4; ++q) {
        int oc = ocg * 4 + q;
        float bi = bias[oc];
        float4 v = make_float4(acc[0][q] + bi, acc[1][q] + bi, acc[2][q] + bi, acc[3][q] + bi);
        *reinterpret_cast<float4*>(out + (size_t)(b * 64 + oc) * HWc + gys * 128 + gx0s) = v;
    }
}

extern "C" void kernel_launch(void* const* d_in, const int* in_sizes, int n_in,
                              void* d_out, int out_size, void* d_ws, size_t ws_size,
                              hipStream_t stream) {
    const float* x      = (const float*)d_in[0];
    const float* w_off  = (const float*)d_in[1];
    const float* cob    = (const float*)d_in[2];
    const float* weight = (const float*)d_in[3];
    const float* bias   = (const float*)d_in[4];
    float* out = (float*)d_out;
    if (ws_size < WS_NEEDED) return;

    char* ws = (char*)d_ws;
    __half* offs = (__half*)ws;
    __half* xTfP = (__half*)(ws + XTFP_OFF);
    __half* wB1  = (__half*)(ws + WB1_OFF);
    __half* wT2  = (__half*)(ws + WT2_OFF);

    hipMemsetAsync(xTfP, 0, XTFP_BYTES, stream);     // zero halo border
    prep_xt<<<1024, 256, 0, stream>>>(x, xTfP);
    prep_w<<<720, 256, 0, stream>>>(w_off, weight, wB1, wT2);
    offset_mfma_k<<<dim3(8, 16, 2), 512, 0, stream>>>(xTfP, wB1, cob, offs);
    dcn_main_k<<<dim3(16, 16, 2), 256, 0, stream>>>(offs, xTfP, wT2, bias, out);
}

// Round 3
// 84.570 us; speedup vs baseline: 3.0001x; 1.5333x over previous
//
#include <hip/hip_runtime.h>
#include <hip/hip_fp16.h>

// DCNv2: B=2, CIN=COUT=64, H=W=128, DG=8, cpg=8, 3x3 s1 p1 d1
constexpr int BB = 2;
constexpr int CINc = 64;
constexpr int HWc = 128 * 128;
constexpr int OCOFFc = 216;   // DG*3*9 offset-conv channels
constexpr int XP = 130;       // padded spatial dim (halo of 1)

// workspace layout (bytes)
constexpr size_t OFFS_BYTES = (size_t)BB * OCOFFc * HWc * 2;        // fp16 offsets+masks
constexpr size_t XTFP_OFF   = OFFS_BYTES;
constexpr size_t XTFP_BYTES = (size_t)BB * XP * XP * 64 * 2;        // padded swizzled x fp16
constexpr size_t WB1_OFF    = XTFP_OFF + XTFP_BYTES;
constexpr size_t WB1_BYTES  = (size_t)9 * 256 * 64 * 2;             // offset W [tap][oc256][slot][8] fp16
constexpr size_t WM_OFF     = WB1_OFF + WB1_BYTES;
constexpr size_t WM_BYTES   = (size_t)8 * 12 * 64 * 8 * 2;          // main W [dg][tap12][oc][8c] fp16
constexpr size_t WS_NEEDED  = WM_OFF + WM_BYTES;                    // ~18.9 MB

typedef _Float16 f16x8 __attribute__((ext_vector_type(8)));
typedef float    f32x4 __attribute__((ext_vector_type(4)));

// ---------- K0a: x -> padded swizzled fp16 [b][y+1][x+1][slot=dg^((x+1)&7)][8ch] ----------
__global__ void prep_xt(const float* __restrict__ x, __half* __restrict__ xTfP) {
    int site = blockIdx.x * 256 + threadIdx.x;      // B*8*HW = 262144
    int pix = site & (HWc - 1);
    int bdg = site >> 14;
    int dg = bdg & 7, b = bdg >> 3;
    int y = pix >> 7, xc = pix & 127;
    const float* xp = x + (size_t)(b * CINc + dg * 8) * HWc + pix;
    __half2 h0 = __halves2half2(__float2half(xp[0 * HWc]), __float2half(xp[1 * HWc]));
    __half2 h1 = __halves2half2(__float2half(xp[2 * HWc]), __float2half(xp[3 * HWc]));
    __half2 h2 = __halves2half2(__float2half(xp[4 * HWc]), __float2half(xp[5 * HWc]));
    __half2 h3 = __halves2half2(__float2half(xp[6 * HWc]), __float2half(xp[7 * HWc]));
    int slot = dg ^ ((xc + 1) & 7);
    __half2* o = reinterpret_cast<__half2*>(
        xTfP + (((size_t)b * XP + y + 1) * XP + xc + 1) * 64 + slot * 8);
    o[0] = h0; o[1] = h1; o[2] = h2; o[3] = h3;
}

// ---------- K0b: weight transforms + xTfP halo zeroing ----------
__global__ void prep_w(const float* __restrict__ w_off, const float* __restrict__ weight,
                       __half* __restrict__ wB1, __half* __restrict__ wM,
                       __half* __restrict__ xTfP) {
    int idx = blockIdx.x * 256 + threadIdx.x;
    if (idx < 9 * 256 * 64) {
        // wB1[tap][oc][sl][ci], slot sl holds cin-group sl^(oc&7)
        int ci = idx & 7;
        int sl = (idx >> 3) & 7;
        int oc = (idx >> 6) & 255;
        int tap = idx >> 14;
        int cin = ((sl ^ (oc & 7)) << 3) + ci;
        float v = (oc < OCOFFc) ? w_off[oc * 576 + cin * 9 + tap] : 0.f;
        wB1[idx] = __float2half(v);
    } else if (idx < 9 * 256 * 64 + 8 * 12 * 64 * 8) {
        int j = idx - 9 * 256 * 64;          // wM[dg][tap12][oc][c]
        int c = j & 7;
        int oc = (j >> 3) & 63;
        int tg = j >> 9;                      // dg*12 + tap
        int tap = tg % 12;
        int dg = tg / 12;
        float v = (tap < 9) ? weight[oc * 576 + (dg * 8 + c) * 9 + tap] : 0.f;
        wM[j] = __float2half(v);
    } else {
        int j2 = idx - (9 * 256 * 64 + 8 * 12 * 64 * 8);   // halo border zeroing
        if (j2 < 8256) {                      // 2b x 516 border px x 8 chunks
            int chunk = j2 & 7;
            int rest = j2 >> 3;
            int p = rest % 516;
            int b = rest / 516;
            int y, x;
            if (p < 130)      { y = 0;           x = p; }
            else if (p < 260) { y = 129;         x = p - 130; }
            else if (p < 388) { y = 1 + p - 260; x = 0; }
            else              { y = 1 + p - 388; x = 129; }
            uint4 z = {0u, 0u, 0u, 0u};
            *reinterpret_cast<uint4*>(
                xTfP + (((size_t)b * XP + y) * XP + x) * 64 + chunk * 8) = z;
        }
    }
}

// ---------- K1: offset conv as implicit-GEMM MFMA (fp16 in, fp32 acc) ----------
// block: 512 thr = 8 waves (2 px-halves x 4 oc-quarters); tile 128px(16x8) x 256oc
__global__ __launch_bounds__(512, 1) void offset_mfma_k(
        const __half* __restrict__ xTfP, const __half* __restrict__ wB1,
        const float* __restrict__ cob, __half* __restrict__ offs) {
    __shared__ __half xs[1440 * 8];    // 23040 B: [10 rows][18 cols][8 slots][8ch]
    __shared__ __half wsh[2048 * 8];   // 32768 B: [256 oc][8 slots][8ch]
    const int tid = threadIdx.x;
    const int bx = blockIdx.x;         // 0..7   (16 px wide)
    const int by = blockIdx.y;         // 0..15  (8 px tall)
    const int b  = blockIdx.z;

    const __half* xg = xTfP + (size_t)b * XP * XP * 64;
    #pragma unroll
    for (int it = 0; it < 3; ++it) {
        int idx = tid + it * 512;
        if (idx < 1440) {
            int yl = idx / 144;                  // 144 = 18 cols * 8 slots
            int rem = idx - yl * 144;
            float4 v = *reinterpret_cast<const float4*>(
                xg + ((size_t)(by * 8 + yl) * XP + bx * 16) * 64 + rem * 8);
            *reinterpret_cast<float4*>(xs + idx * 8) = v;
        }
    }

    const int lane = tid & 63;
    const int wid = tid >> 6;
    const int wr = wid & 1;            // px half (4 rows each)
    const int wc = wid >> 1;           // oc quarter (64 oc each)
    const int l15 = lane & 15, lh = lane >> 4;

    f32x4 acc[4][4];
    const f32x4 zero = {0.f, 0.f, 0.f, 0.f};
    #pragma unroll
    for (int ty = 0; ty < 4; ++ty)
        #pragma unroll
        for (int ot = 0; ot < 4; ++ot) acc[ty][ot] = zero;

    float4 wreg[4];
    #pragma unroll
    for (int i = 0; i < 4; ++i)
        wreg[i] = *reinterpret_cast<const float4*>(wB1 + (size_t)(tid + i * 512) * 8);
    __syncthreads();   // xs ready

    for (int tap = 0; tap < 9; ++tap) {
        #pragma unroll
        for (int i = 0; i < 4; ++i)
            *reinterpret_cast<float4*>(wsh + (size_t)(tid + i * 512) * 8) = wreg[i];
        __syncthreads();   // wsh ready
        if (tap < 8) {
            #pragma unroll
            for (int i = 0; i < 4; ++i)
                wreg[i] = *reinterpret_cast<const float4*>(
                    wB1 + (size_t)(tap + 1) * 16384 + (size_t)(tid + i * 512) * 8);
        }
        const int r = tap / 3, s = tap - r * 3;
        const int j = l15 + s;                    // patch col
        #pragma unroll
        for (int h = 0; h < 2; ++h) {
            const int c = h * 4 + lh;             // cin group 0..7
            const int sl = c ^ (j & 7);
            f16x8 af[4], bf[4];
            #pragma unroll
            for (int ty = 0; ty < 4; ++ty) {
                int row = wr * 4 + ty + r;
                af[ty] = *reinterpret_cast<const f16x8*>(xs + (row * 18 + j) * 64 + sl * 8);
            }
            #pragma unroll
            for (int ot = 0; ot < 4; ++ot) {
                int oc = wc * 64 + ot * 16 + l15;
                int slw = c ^ (oc & 7);
                bf[ot] = *reinterpret_cast<const f16x8*>(wsh + oc * 64 + slw * 8);
            }
            #pragma unroll
            for (int ty = 0; ty < 4; ++ty)
                #pragma unroll
                for (int ot = 0; ot < 4; ++ot)
                    acc[ty][ot] = __builtin_amdgcn_mfma_f32_16x16x32_f16(
                        af[ty], bf[ot], acc[ty][ot], 0, 0, 0);
        }
        __syncthreads();   // protect wsh before next overwrite
    }

    #pragma unroll
    for (int ot = 0; ot < 4; ++ot) {
        int oc = wc * 64 + ot * 16 + l15;
        if (oc >= OCOFFc) continue;
        float bi = cob[oc];
        bool sig = (oc >= 144);
        #pragma unroll
        for (int ty = 0; ty < 4; ++ty) {
            int gy = by * 8 + wr * 4 + ty;
            int gx = bx * 16 + lh * 4;
            float v0 = acc[ty][ot][0] + bi, v1 = acc[ty][ot][1] + bi;
            float v2 = acc[ty][ot][2] + bi, v3 = acc[ty][ot][3] + bi;
            if (sig) {
                v0 = 1.f / (1.f + __expf(-v0)); v1 = 1.f / (1.f + __expf(-v1));
                v2 = 1.f / (1.f + __expf(-v2)); v3 = 1.f / (1.f + __expf(-v3));
            }
            __half* dst = offs + (size_t)(b * OCOFFc + oc) * HWc + gy * 128 + gx;
            reinterpret_cast<__half2*>(dst)[0] = __halves2half2(__float2half(v0), __float2half(v1));
            reinterpret_cast<__half2*>(dst)[1] = __halves2half2(__float2half(v2), __float2half(v3));
        }
    }
}

// ---------- K2: bilinear sampling (half2 blend) + main conv on MFMA ----------
// block: 256 thr = 4 waves; tile 64px(8x8) x 64oc; dg-loop with K=96 (72 real) per dg
__global__ __launch_bounds__(256, 2) void dcn_main_k(
        const __half* __restrict__ offs, const __half* __restrict__ xTfP,
        const __half* __restrict__ wM, const float* __restrict__ bias,
        float* __restrict__ out) {
    __shared__ __align__(16) __half col[12 * 64 * 8];   // [kg=tap][px][8c]  12288 B
    __shared__ __align__(16) __half wsl[12 * 64 * 8];   // [kg=tap][oc][8c]  12288 B
    const int tid = threadIdx.x;
    const int tx = blockIdx.x, ty = blockIdx.y, b = blockIdx.z;
    const int lane = tid & 63, wid = tid >> 6;
    const int l15 = lane & 15, lh = lane >> 4;

    // zero pad taps 9..11 of col (written once, never overwritten)
    if (tid < 192) {
        uint4 z = {0u, 0u, 0u, 0u};
        *reinterpret_cast<uint4*>(col + (9 * 64 + tid) * 8) = z;
    }

    f32x4 acc[4];
    const f32x4 zero = {0.f, 0.f, 0.f, 0.f};
    #pragma unroll
    for (int n = 0; n < 4; ++n) acc[n] = zero;

    // prologue: weights for dg 0
    float4 wreg[3];
    #pragma unroll
    for (int i = 0; i < 3; ++i)
        wreg[i] = *reinterpret_cast<const float4*>(wM + (size_t)(tid + i * 256) * 8);

    const __half* xb = xTfP + (size_t)b * XP * XP * 64;

    #pragma unroll 1
    for (int dg = 0; dg < 8; ++dg) {
        __syncthreads();   // col & wsl free (prev MFMA done)
        #pragma unroll
        for (int i = 0; i < 3; ++i)
            *reinterpret_cast<float4*>(wsl + (tid + i * 256) * 8) = wreg[i];
        if (dg < 7) {
            #pragma unroll
            for (int i = 0; i < 3; ++i)
                wreg[i] = *reinterpret_cast<const float4*>(
                    wM + (size_t)((dg + 1) * 768 + tid + i * 256) * 8);
        }
        // sampling: 576 sites (9 taps x 64 px), k uniform per wave
        #pragma unroll
        for (int it = 0; it < 3; ++it) {
            int j = tid + it * 256;
            if (j < 576) {
                const int px = j & 63;
                const int k = j >> 6;
                const int gy = ty * 8 + (px >> 3), gx = tx * 8 + (px & 7);
                const int pix = gy * 128 + gx;
                const int dgk = dg * 9 + k;
                float oy = __half2float(offs[(size_t)(b * 216 + dgk * 2) * HWc + pix]);
                float ox = __half2float(offs[(size_t)(b * 216 + dgk * 2 + 1) * HWc + pix]);
                float m  = __half2float(offs[(size_t)(b * 216 + 144 + dgk) * HWc + pix]);
                const int ki = k / 3, kj = k - ki * 3;
                float sy = oy + (float)(gy - 1 + ki);
                float sx = ox + (float)(gx - 1 + kj);
                float y0f = floorf(sy), x0f = floorf(sx);
                int iy0 = (int)y0f, ix0 = (int)x0f;
                float ly = sy - y0f, lx = sx - x0f;
                float hy = 1.f - ly, hx = 1.f - lx;
                float vy0 = ((unsigned)iy0 < 128u) ? 1.f : 0.f;
                float vy1 = ((unsigned)(iy0 + 1) < 128u) ? 1.f : 0.f;
                float vx0 = ((unsigned)ix0 < 128u) ? 1.f : 0.f;
                float vx1 = ((unsigned)(ix0 + 1) < 128u) ? 1.f : 0.f;
                float w00 = hy * hx * vy0 * vx0 * m, w01 = hy * lx * vy0 * vx1 * m;
                float w10 = ly * hx * vy1 * vx0 * m, w11 = ly * lx * vy1 * vx1 * m;
                int y0c = min(max(iy0, 0), 127), y1c = min(max(iy0 + 1, 0), 127);
                int x0c = min(max(ix0, 0), 127), x1c = min(max(ix0 + 1, 0), 127);
                float4 f00 = *reinterpret_cast<const float4*>(
                    xb + ((size_t)(y0c + 1) * XP + x0c + 1) * 64 + ((dg ^ ((x0c + 1) & 7)) << 3));
                float4 f01 = *reinterpret_cast<const float4*>(
                    xb + ((size_t)(y0c + 1) * XP + x1c + 1) * 64 + ((dg ^ ((x1c + 1) & 7)) << 3));
                float4 f10 = *reinterpret_cast<const float4*>(
                    xb + ((size_t)(y1c + 1) * XP + x0c + 1) * 64 + ((dg ^ ((x0c + 1) & 7)) << 3));
                float4 f11 = *reinterpret_cast<const float4*>(
                    xb + ((size_t)(y1c + 1) * XP + x1c + 1) * 64 + ((dg ^ ((x1c + 1) & 7)) << 3));
                const __half2* a00 = reinterpret_cast<const __half2*>(&f00);
                const __half2* a01 = reinterpret_cast<const __half2*>(&f01);
                const __half2* a10 = reinterpret_cast<const __half2*>(&f10);
                const __half2* a11 = reinterpret_cast<const __half2*>(&f11);
                __half2 W00 = __float2half2_rn(w00), W01 = __float2half2_rn(w01);
                __half2 W10 = __float2half2_rn(w10), W11 = __float2half2_rn(w11);
                __half2 rr[4];
                #pragma unroll
                for (int cc = 0; cc < 4; ++cc)
                    rr[cc] = __hfma2(a00[cc], W00,
                             __hfma2(a01[cc], W01,
                             __hfma2(a10[cc], W10, __hmul2(a11[cc], W11))));
                *reinterpret_cast<uint4*>(col + ((k * 64 + px) * 8)) =
                    *reinterpret_cast<const uint4*>(rr);
            }
        }
        __syncthreads();   // col & wsl ready
        // MFMA: M=64px (wave-tiled), N=64oc, K=96
        #pragma unroll
        for (int s = 0; s < 3; ++s) {
            int kg = s * 4 + lh;
            f16x8 af = *reinterpret_cast<const f16x8*>(col + (kg * 64 + wid * 16 + l15) * 8);
            #pragma unroll
            for (int n = 0; n < 4; ++n) {
                f16x8 bf = *reinterpret_cast<const f16x8*>(wsl + (kg * 64 + n * 16 + l15) * 8);
                acc[n] = __builtin_amdgcn_mfma_f32_16x16x32_f16(af, bf, acc[n], 0, 0, 0);
            }
        }
    }

    // epilogue: D[row=px][col=oc]; px = wid*16 + lh*4 + reg
    const int pxb = wid * 16 + lh * 4;
    const int py = pxb >> 3, gxl = pxb & 7;
    float* obase = out + (size_t)b * 64 * HWc + (ty * 8 + py) * 128 + tx * 8 + gxl;
    #pragma unroll
    for (int n = 0; n < 4; ++n) {
        int oc = n * 16 + l15;
        float bi = bias[oc];
        float4 v = make_float4(acc[n][0] + bi, acc[n][1] + bi, acc[n][2] + bi, acc[n][3] + bi);
        *reinterpret_cast<float4*>(obase + (size_t)oc * HWc) = v;
    }
}

extern "C" void kernel_launch(void* const* d_in, const int* in_sizes, int n_in,
                              void* d_out, int out_size, void* d_ws, size_t ws_size,
                              hipStream_t stream) {
    const float* x      = (const float*)d_in[0];
    const float* w_off  = (const float*)d_in[1];
    const float* cob    = (const float*)d_in[2];
    const float* weight = (const float*)d_in[3];
    const float* bias   = (const float*)d_in[4];
    float* out = (float*)d_out;
    if (ws_size < WS_NEEDED) return;

    char* ws = (char*)d_ws;
    __half* offs = (__half*)ws;
    __half* xTfP = (__half*)(ws + XTFP_OFF);
    __half* wB1  = (__half*)(ws + WB1_OFF);
    __half* wM   = (__half*)(ws + WM_OFF);

    prep_xt<<<1024, 256, 0, stream>>>(x, xTfP);
    prep_w<<<801, 256, 0, stream>>>(w_off, weight, wB1, wM, xTfP);
    offset_mfma_k<<<dim3(8, 16, 2), 512, 0, stream>>>(xTfP, wB1, cob, offs);
    dcn_main_k<<<dim3(16, 16, 2), 256, 0, stream>>>(offs, xTfP, wM, bias, out);
}

// Round 4
// 60.342 us; speedup vs baseline: 4.2047x; 1.4015x over previous
//
#include <hip/hip_runtime.h>
#include <hip/hip_fp16.h>

// DCNv2: B=2, CIN=COUT=64, H=W=128, DG=8, cpg=8, 3x3 s1 p1 d1
constexpr int BB = 2;
constexpr int CINc = 64;
constexpr int HWc = 128 * 128;
constexpr int OCOFFc = 216;   // DG*3*9 offset-conv channels
constexpr int XP = 130;       // padded spatial dim (halo of 1)

// workspace layout (bytes)
// offsT: [b][tile(16x16 of 8x8px)][dg][k][{oy,ox,m}][64px] fp16
constexpr size_t OFFS_BYTES = (size_t)BB * 256 * 8 * 9 * 3 * 64 * 2;   // 14.16 MB
constexpr size_t XT_OFF     = OFFS_BYTES;
constexpr size_t XT_BYTES   = (size_t)BB * 8 * XP * XP * 8 * 2;        // per-(b,dg) planes, 16B/px
constexpr size_t WB1_OFF    = XT_OFF + XT_BYTES;
constexpr size_t WB1_BYTES  = (size_t)9 * 256 * 64 * 2;                // offset W [tap][oc256][sl][8] fp16
constexpr size_t WM_OFF     = WB1_OFF + WB1_BYTES;
constexpr size_t WM_BYTES   = (size_t)8 * 12 * 64 * 8 * 2;             // main W [dg][tap12][oc][8c] fp16
constexpr size_t WS_NEEDED  = WM_OFF + WM_BYTES;                       // ~18.9 MB

typedef _Float16 f16x8 __attribute__((ext_vector_type(8)));
typedef float    f32x4 __attribute__((ext_vector_type(4)));

// ---------- K0a: x -> per-(b,dg) padded planes [b*8+dg][y+1][x+1][8ch] fp16 ----------
__global__ void prep_xt(const float* __restrict__ x, __half* __restrict__ xT) {
    int site = blockIdx.x * 256 + threadIdx.x;      // B*8*HW = 262144
    int pix = site & (HWc - 1);
    int bdg = site >> 14;
    int dg = bdg & 7, b = bdg >> 3;
    int y = pix >> 7, xc = pix & 127;
    const float* xp = x + (size_t)(b * CINc + dg * 8) * HWc + pix;
    __half2 h0 = __halves2half2(__float2half(xp[0 * HWc]), __float2half(xp[1 * HWc]));
    __half2 h1 = __halves2half2(__float2half(xp[2 * HWc]), __float2half(xp[3 * HWc]));
    __half2 h2 = __halves2half2(__float2half(xp[4 * HWc]), __float2half(xp[5 * HWc]));
    __half2 h3 = __halves2half2(__float2half(xp[6 * HWc]), __float2half(xp[7 * HWc]));
    __half2* o = reinterpret_cast<__half2*>(
        xT + (((size_t)(b * 8 + dg) * XP + y + 1) * XP + xc + 1) * 8);
    o[0] = h0; o[1] = h1; o[2] = h2; o[3] = h3;
}

// ---------- K0b: weight transforms + plane halo zeroing ----------
__global__ void prep_w(const float* __restrict__ w_off, const float* __restrict__ weight,
                       __half* __restrict__ wB1, __half* __restrict__ wM,
                       __half* __restrict__ xT) {
    int idx = blockIdx.x * 256 + threadIdx.x;
    if (idx < 9 * 256 * 64) {
        // wB1[tap][oc][sl][ci], slot sl holds cin-group sl^(oc&7)
        int ci = idx & 7;
        int sl = (idx >> 3) & 7;
        int oc = (idx >> 6) & 255;
        int tap = idx >> 14;
        int cin = ((sl ^ (oc & 7)) << 3) + ci;
        float v = (oc < OCOFFc) ? w_off[oc * 576 + cin * 9 + tap] : 0.f;
        wB1[idx] = __float2half(v);
    } else if (idx < 9 * 256 * 64 + 8 * 12 * 64 * 8) {
        int j = idx - 9 * 256 * 64;          // wM[dg][tap12][oc][c]
        int c = j & 7;
        int oc = (j >> 3) & 63;
        int tg = j >> 9;                      // dg*12 + tap
        int tap = tg % 12;
        int dg = tg / 12;
        float v = (tap < 9) ? weight[oc * 576 + (dg * 8 + c) * 9 + tap] : 0.f;
        wM[j] = __float2half(v);
    } else {
        int j2 = idx - (9 * 256 * 64 + 8 * 12 * 64 * 8);   // halo zero: 16 planes x 516 px
        if (j2 < 16 * 516) {
            int plane = j2 / 516;
            int p = j2 - plane * 516;
            int y, x;
            if (p < 130)      { y = 0;           x = p; }
            else if (p < 260) { y = 129;         x = p - 130; }
            else if (p < 388) { y = 1 + p - 260; x = 0; }
            else              { y = 1 + p - 388; x = 129; }
            uint4 z = {0u, 0u, 0u, 0u};
            *reinterpret_cast<uint4*>(xT + (((size_t)plane * XP + y) * XP + x) * 8) = z;
        }
    }
}

// ---------- K1: offset conv, implicit-GEMM MFMA, 128px x 128oc per block ----------
// 256 thr = 4 waves (2 y-halves x 2 oc-halves); dbuf weights, 1 barrier/tap
__global__ __launch_bounds__(256, 2) void offset_mfma_k(
        const __half* __restrict__ xT, const __half* __restrict__ wB1,
        const float* __restrict__ cob, __half* __restrict__ offsT) {
    __shared__ __half xs[1440 * 8];       // 23040 B: [row10][col18][sl8][8ch]
    __shared__ __half wsh[2][1024 * 8];   // 2x16 KB: [ocl128][sl8][8ch]
    const int tid = threadIdx.x;
    const int bx = blockIdx.x;            // 0..7   (16 px wide)
    const int by = blockIdx.y;            // 0..15  (8 px tall)
    const int bz = blockIdx.z;            // b*2 + bo
    const int b = bz >> 1, bo = bz & 1;

    // stage x patch from 8 dg-planes with LDS XOR swizzle (sl = dg^(col&7))
    #pragma unroll
    for (int it = 0; it < 6; ++it) {
        int idx = tid + it * 256;
        if (idx < 1440) {
            int yl = idx / 144;                  // 144 = 18 cols * 8 slots
            int rem = idx - yl * 144;
            int cl = rem >> 3, sl = rem & 7;
            int dg = sl ^ (cl & 7);
            float4 v = *reinterpret_cast<const float4*>(
                xT + (((size_t)(b * 8 + dg) * XP + by * 8 + yl) * XP + bx * 16 + cl) * 8);
            *reinterpret_cast<float4*>(xs + idx * 8) = v;
        }
    }
    // W(0) -> regs -> wsh[0]
    float4 wreg[4];
    #pragma unroll
    for (int i = 0; i < 4; ++i)
        wreg[i] = *reinterpret_cast<const float4*>(
            wB1 + ((size_t)bo * 8192 + (tid + i * 256) * 8));
    #pragma unroll
    for (int i = 0; i < 4; ++i)
        *reinterpret_cast<float4*>(&wsh[0][(tid + i * 256) * 8]) = wreg[i];
    __syncthreads();

    const int lane = tid & 63;
    const int wid = tid >> 6;
    const int wr = wid & 1;            // y half (4 rows)
    const int wc = wid >> 1;           // oc half (64 of 128)
    const int l15 = lane & 15, lh = lane >> 4;

    f32x4 acc[4][4];
    const f32x4 zero = {0.f, 0.f, 0.f, 0.f};
    #pragma unroll
    for (int ty = 0; ty < 4; ++ty)
        #pragma unroll
        for (int ot = 0; ot < 4; ++ot) acc[ty][ot] = zero;

    for (int tap = 0; tap < 9; ++tap) {
        const int cur = tap & 1;
        if (tap < 8) {
            #pragma unroll
            for (int i = 0; i < 4; ++i)
                wreg[i] = *reinterpret_cast<const float4*>(
                    wB1 + ((size_t)(tap + 1) * 16384 + bo * 8192 + (tid + i * 256) * 8));
        }
        const int r = tap / 3, s = tap - r * 3;
        const int j = l15 + s;                    // patch col
        #pragma unroll
        for (int h = 0; h < 2; ++h) {
            const int c = h * 4 + lh;             // cin group 0..7
            const int sl = c ^ (j & 7);
            f16x8 af[4], bf[4];
            #pragma unroll
            for (int ty = 0; ty < 4; ++ty) {
                int row = wr * 4 + ty + r;
                af[ty] = *reinterpret_cast<const f16x8*>(xs + (row * 18 + j) * 64 + sl * 8);
            }
            #pragma unroll
            for (int ot = 0; ot < 4; ++ot) {
                int ocl = wc * 64 + ot * 16 + l15;
                int slw = c ^ (ocl & 7);
                bf[ot] = *reinterpret_cast<const f16x8*>(&wsh[cur][ocl * 64 + slw * 8]);
            }
            #pragma unroll
            for (int ty = 0; ty < 4; ++ty)
                #pragma unroll
                for (int ot = 0; ot < 4; ++ot)
                    acc[ty][ot] = __builtin_amdgcn_mfma_f32_16x16x32_f16(
                        af[ty], bf[ot], acc[ty][ot], 0, 0, 0);
        }
        if (tap < 8) {
            #pragma unroll
            for (int i = 0; i < 4; ++i)
                *reinterpret_cast<float4*>(&wsh[cur ^ 1][(tid + i * 256) * 8]) = wreg[i];
        }
        __syncthreads();
    }

    // epilogue -> offsT tile layout; D: col(oc)=l15, row(px-x)=lh*4+j
    #pragma unroll
    for (int ot = 0; ot < 4; ++ot) {
        int ocl = wc * 64 + ot * 16 + l15;
        int oc = bo * 128 + ocl;
        if (oc >= OCOFFc) continue;
        float bi = cob[oc];
        bool sig = (oc >= 144);
        int dg, k, comp;
        if (oc < 144) { dg = oc / 18; int rem = oc - dg * 18; k = rem >> 1; comp = rem & 1; }
        else          { int mm = oc - 144; dg = mm / 9; k = mm - dg * 9; comp = 2; }
        int tile = by * 16 + bx * 2 + (lh >> 1);
        __half* dstb = offsT + ((((size_t)(b * 256 + tile) * 8 + dg) * 9 + k) * 3 + comp) * 64
                       + (lh & 1) * 4;
        #pragma unroll
        for (int ty = 0; ty < 4; ++ty) {
            float v0 = acc[ty][ot][0] + bi, v1 = acc[ty][ot][1] + bi;
            float v2 = acc[ty][ot][2] + bi, v3 = acc[ty][ot][3] + bi;
            if (sig) {
                v0 = 1.f / (1.f + __expf(-v0)); v1 = 1.f / (1.f + __expf(-v1));
                v2 = 1.f / (1.f + __expf(-v2)); v3 = 1.f / (1.f + __expf(-v3));
            }
            __half2* dst = reinterpret_cast<__half2*>(dstb + (wr * 4 + ty) * 8);
            dst[0] = __halves2half2(__float2half(v0), __float2half(v1));
            dst[1] = __halves2half2(__float2half(v2), __float2half(v3));
        }
    }
}

// ---------- K2: bilinear sampling + main conv MFMA; dbuf col+wsl, 1 barrier/dg ----------
__global__ __launch_bounds__(256, 2) void dcn_main_k(
        const __half* __restrict__ offsT, const __half* __restrict__ xT,
        const __half* __restrict__ wM, const float* __restrict__ bias,
        float* __restrict__ out) {
    __shared__ __align__(16) __half col[2][12 * 64 * 8];   // 2x12 KB [kg][px][8c]
    __shared__ __align__(16) __half wsl[2][12 * 64 * 8];   // 2x12 KB [kg][oc][8c]
    const int tid = threadIdx.x;
    const int tx = blockIdx.x, ty = blockIdx.y, b = blockIdx.z;
    const int lane = tid & 63, wid = tid >> 6;
    const int l15 = lane & 15, lh = lane >> 4;

    // zero pad taps 9..11 of both col buffers (written once)
    #pragma unroll
    for (int it = 0; it < 2; ++it) {
        int idx = tid + it * 256;
        if (idx < 384) {
            int buf = idx / 192, rest = idx - buf * 192;
            uint4 z = {0u, 0u, 0u, 0u};
            *reinterpret_cast<uint4*>(&col[buf][(9 * 64 + rest) * 8]) = z;
        }
    }

    f32x4 acc[4];
    const f32x4 zero = {0.f, 0.f, 0.f, 0.f};
    #pragma unroll
    for (int n = 0; n < 4; ++n) acc[n] = zero;

    // prefetch W(0)
    float4 wreg[3];
    #pragma unroll
    for (int i = 0; i < 3; ++i)
        wreg[i] = *reinterpret_cast<const float4*>(wM + (size_t)(tid + i * 256) * 8);

    const __half* tb = offsT + (size_t)(b * 256 + ty * 16 + tx) * 8 * 9 * 3 * 64;

    #pragma unroll 1
    for (int dg = 0; dg < 8; ++dg) {
        const int cur = dg & 1;
        // sampling: 576 sites (9 taps x 64 px) -> col[cur]
        const __half* xb = xT + (size_t)(b * 8 + dg) * XP * XP * 8;
        #pragma unroll
        for (int it = 0; it < 3; ++it) {
            int j = tid + it * 256;
            if (j < 576) {
                const int px = j & 63;
                const int k = j >> 6;
                const int gy = ty * 8 + (px >> 3), gx = tx * 8 + (px & 7);
                const __half* op = tb + (dg * 9 + k) * 192;
                float oy = __half2float(op[px]);
                float ox = __half2float(op[64 + px]);
                float m  = __half2float(op[128 + px]);
                const int ki = k / 3, kj = k - ki * 3;
                float sy = oy + (float)(gy - 1 + ki);
                float sx = ox + (float)(gx - 1 + kj);
                float y0f = floorf(sy), x0f = floorf(sx);
                int iy0 = (int)y0f, ix0 = (int)x0f;
                float ly = sy - y0f, lx = sx - x0f;
                float hy = 1.f - ly, hx = 1.f - lx;
                float vy0 = ((unsigned)iy0 < 128u) ? 1.f : 0.f;
                float vy1 = ((unsigned)(iy0 + 1) < 128u) ? 1.f : 0.f;
                float vx0 = ((unsigned)ix0 < 128u) ? 1.f : 0.f;
                float vx1 = ((unsigned)(ix0 + 1) < 128u) ? 1.f : 0.f;
                float w00 = hy * hx * vy0 * vx0 * m, w01 = hy * lx * vy0 * vx1 * m;
                float w10 = ly * hx * vy1 * vx0 * m, w11 = ly * lx * vy1 * vx1 * m;
                int y0c = min(max(iy0, 0), 127), y1c = min(max(iy0 + 1, 0), 127);
                int x0c = min(max(ix0, 0), 127), x1c = min(max(ix0 + 1, 0), 127);
                float4 f00 = *reinterpret_cast<const float4*>(xb + ((size_t)(y0c + 1) * XP + x0c + 1) * 8);
                float4 f01 = *reinterpret_cast<const float4*>(xb + ((size_t)(y0c + 1) * XP + x1c + 1) * 8);
                float4 f10 = *reinterpret_cast<const float4*>(xb + ((size_t)(y1c + 1) * XP + x0c + 1) * 8);
                float4 f11 = *reinterpret_cast<const float4*>(xb + ((size_t)(y1c + 1) * XP + x1c + 1) * 8);
                const __half2* a00 = reinterpret_cast<const __half2*>(&f00);
                const __half2* a01 = reinterpret_cast<const __half2*>(&f01);
                const __half2* a10 = reinterpret_cast<const __half2*>(&f10);
                const __half2* a11 = reinterpret_cast<const __half2*>(&f11);
                __half2 W00 = __float2half2_rn(w00), W01 = __float2half2_rn(w01);
                __half2 W10 = __float2half2_rn(w10), W11 = __float2half2_rn(w11);
                __half2 rr[4];
                #pragma unroll
                for (int cc = 0; cc < 4; ++cc)
                    rr[cc] = __hfma2(a00[cc], W00,
                             __hfma2(a01[cc], W01,
                             __hfma2(a10[cc], W10, __hmul2(a11[cc], W11))));
                *reinterpret_cast<uint4*>(&col[cur][(k * 64 + px) * 8]) =
                    *reinterpret_cast<const uint4*>(rr);
            }
        }
        // weights: regs(dg) -> wsl[cur]; prefetch dg+1
        #pragma unroll
        for (int i = 0; i < 3; ++i)
            *reinterpret_cast<float4*>(&wsl[cur][(tid + i * 256) * 8]) = wreg[i];
        if (dg < 7) {
            #pragma unroll
            for (int i = 0; i < 3; ++i)
                wreg[i] = *reinterpret_cast<const float4*>(
                    wM + (size_t)((dg + 1) * 768 + tid + i * 256) * 8);
        }
        __syncthreads();   // col[cur], wsl[cur] ready
        // MFMA: 16px/wave x 64oc, K=96
        #pragma unroll
        for (int s = 0; s < 3; ++s) {
            int kg = s * 4 + lh;
            f16x8 af = *reinterpret_cast<const f16x8*>(&col[cur][(kg * 64 + wid * 16 + l15) * 8]);
            #pragma unroll
            for (int n = 0; n < 4; ++n) {
                f16x8 bf = *reinterpret_cast<const f16x8*>(&wsl[cur][(kg * 64 + n * 16 + l15) * 8]);
                acc[n] = __builtin_amdgcn_mfma_f32_16x16x32_f16(af, bf, acc[n], 0, 0, 0);
            }
        }
        // no trailing barrier: next iter writes the other buffer
    }

    // epilogue: D[row=px][col=oc]; px = wid*16 + lh*4 + reg
    const int pxb = wid * 16 + lh * 4;
    const int py = pxb >> 3, gxl = pxb & 7;
    float* obase = out + (size_t)b * 64 * HWc + (ty * 8 + py) * 128 + tx * 8 + gxl;
    #pragma unroll
    for (int n = 0; n < 4; ++n) {
        int oc = n * 16 + l15;
        float bi = bias[oc];
        float4 v = make_float4(acc[n][0] + bi, acc[n][1] + bi, acc[n][2] + bi, acc[n][3] + bi);
        *reinterpret_cast<float4*>(obase + (size_t)oc * HWc) = v;
    }
}

extern "C" void kernel_launch(void* const* d_in, const int* in_sizes, int n_in,
                              void* d_out, int out_size, void* d_ws, size_t ws_size,
                              hipStream_t stream) {
    const float* x      = (const float*)d_in[0];
    const float* w_off  = (const float*)d_in[1];
    const float* cob    = (const float*)d_in[2];
    const float* weight = (const float*)d_in[3];
    const float* bias   = (const float*)d_in[4];
    float* out = (float*)d_out;
    if (ws_size < WS_NEEDED) return;

    char* ws = (char*)d_ws;
    __half* offsT = (__half*)ws;
    __half* xT    = (__half*)(ws + XT_OFF);
    __half* wB1   = (__half*)(ws + WB1_OFF);
    __half* wM    = (__half*)(ws + WM_OFF);

    prep_xt<<<1024, 256, 0, stream>>>(x, xT);
    prep_w<<<801, 256, 0, stream>>>(w_off, weight, wB1, wM, xT);
    offset_mfma_k<<<dim3(8, 16, 4), 256, 0, stream>>>(xT, wB1, cob, offsT);
    dcn_main_k<<<dim3(16, 16, 2), 256, 0, stream>>>(offsT, xT, wM, bias, out);
}

// Round 5
// 51.746 us; speedup vs baseline: 4.9032x; 1.1661x over previous
//
#include <hip/hip_runtime.h>
#include <hip/hip_fp16.h>

// DCNv2: B=2, CIN=COUT=64, H=W=128, DG=8, cpg=8, 3x3 s1 p1 d1
constexpr int BB = 2;
constexpr int CINc = 64;
constexpr int HWc = 128 * 128;
constexpr int OCOFFc = 216;   // DG*3*9 offset-conv channels
constexpr int XP = 130;       // padded spatial dim (halo of 1)

// workspace layout (bytes)
// offsT: [b][tile(16x16 of 8x8px)][dg][k][{oy,ox,m}][64px] fp16
constexpr size_t OFFS_BYTES = (size_t)BB * 256 * 8 * 9 * 3 * 64 * 2;   // 14.16 MB
constexpr size_t XT_OFF     = OFFS_BYTES;
constexpr size_t XT_BYTES   = (size_t)BB * 8 * XP * XP * 8 * 2;        // per-(b,dg) planes, 16B/px
constexpr size_t WB1_OFF    = XT_OFF + XT_BYTES;
constexpr size_t WB1_BYTES  = (size_t)9 * 256 * 64 * 2;                // offset W [tap][oc256][sl][8] fp16
constexpr size_t WM_OFF     = WB1_OFF + WB1_BYTES;
constexpr size_t WM_BYTES   = (size_t)8 * 12 * 64 * 8 * 2;             // main W [dg][tap12][oc][8c] fp16
constexpr size_t WS_NEEDED  = WM_OFF + WM_BYTES;                       // ~18.9 MB

typedef _Float16 f16x8 __attribute__((ext_vector_type(8)));
typedef float    f32x4 __attribute__((ext_vector_type(4)));

// ---------- K0: fused prep: x->planes, weight transforms, halo zero ----------
__global__ void prep_all(const float* __restrict__ x, const float* __restrict__ w_off,
                         const float* __restrict__ weight,
                         __half* __restrict__ xT, __half* __restrict__ wB1,
                         __half* __restrict__ wM) {
    int bid = blockIdx.x;
    if (bid < 1024) {
        int site = bid * 256 + threadIdx.x;      // B*8*HW = 262144
        int pix = site & (HWc - 1);
        int bdg = site >> 14;
        int dg = bdg & 7, b = bdg >> 3;
        int y = pix >> 7, xc = pix & 127;
        const float* xp = x + (size_t)(b * CINc + dg * 8) * HWc + pix;
        __half2 h0 = __halves2half2(__float2half(xp[0 * HWc]), __float2half(xp[1 * HWc]));
        __half2 h1 = __halves2half2(__float2half(xp[2 * HWc]), __float2half(xp[3 * HWc]));
        __half2 h2 = __halves2half2(__float2half(xp[4 * HWc]), __float2half(xp[5 * HWc]));
        __half2 h3 = __halves2half2(__float2half(xp[6 * HWc]), __float2half(xp[7 * HWc]));
        __half2* o = reinterpret_cast<__half2*>(
            xT + (((size_t)(b * 8 + dg) * XP + y + 1) * XP + xc + 1) * 8);
        o[0] = h0; o[1] = h1; o[2] = h2; o[3] = h3;
        return;
    }
    int idx = (bid - 1024) * 256 + threadIdx.x;
    if (idx < 9 * 256 * 64) {
        // wB1[tap][oc][sl][ci], slot sl holds cin-group sl^(oc&7)
        int ci = idx & 7;
        int sl = (idx >> 3) & 7;
        int oc = (idx >> 6) & 255;
        int tap = idx >> 14;
        int cin = ((sl ^ (oc & 7)) << 3) + ci;
        float v = (oc < OCOFFc) ? w_off[oc * 576 + cin * 9 + tap] : 0.f;
        wB1[idx] = __float2half(v);
    } else if (idx < 9 * 256 * 64 + 8 * 12 * 64 * 8) {
        int j = idx - 9 * 256 * 64;          // wM[dg][tap12][oc][c]
        int c = j & 7;
        int oc = (j >> 3) & 63;
        int tg = j >> 9;                      // dg*12 + tap
        int tap = tg % 12;
        int dg = tg / 12;
        float v = (tap < 9) ? weight[oc * 576 + (dg * 8 + c) * 9 + tap] : 0.f;
        wM[j] = __float2half(v);
    } else {
        int j2 = idx - (9 * 256 * 64 + 8 * 12 * 64 * 8);   // halo zero: 16 planes x 516 px
        if (j2 < 16 * 516) {
            int plane = j2 / 516;
            int p = j2 - plane * 516;
            int y, xx;
            if (p < 130)      { y = 0;           xx = p; }
            else if (p < 260) { y = 129;         xx = p - 130; }
            else if (p < 388) { y = 1 + p - 260; xx = 0; }
            else              { y = 1 + p - 388; xx = 129; }
            uint4 z = {0u, 0u, 0u, 0u};
            *reinterpret_cast<uint4*>(xT + (((size_t)plane * XP + y) * XP + xx) * 8) = z;
        }
    }
}

// ---------- K1: offset conv, implicit-GEMM MFMA, 128px x 256oc, 8 waves ----------
__global__ __launch_bounds__(512, 2) void offset_mfma_k(
        const __half* __restrict__ xT, const __half* __restrict__ wB1,
        const float* __restrict__ cob, __half* __restrict__ offsT) {
    __shared__ __half xs[1440 * 8];       // 23040 B: [row10][col18][sl8][8ch]
    __shared__ __half wsh[2][2048 * 8];   // 2x32 KB: [oc256][sl8][8ch]
    const int tid = threadIdx.x;
    const int bx = blockIdx.x;            // 0..7   (16 px wide)
    const int by = blockIdx.y;            // 0..15  (8 px tall)
    const int b  = blockIdx.z;

    // stage x patch from 8 dg-planes with LDS XOR swizzle (sl = dg^(col&7))
    #pragma unroll
    for (int it = 0; it < 3; ++it) {
        int idx = tid + it * 512;
        if (idx < 1440) {
            int yl = idx / 144;                  // 144 = 18 cols * 8 slots
            int rem = idx - yl * 144;
            int cl = rem >> 3, sl = rem & 7;
            int dg = sl ^ (cl & 7);
            float4 v = *reinterpret_cast<const float4*>(
                xT + (((size_t)(b * 8 + dg) * XP + by * 8 + yl) * XP + bx * 16 + cl) * 8);
            *reinterpret_cast<float4*>(xs + idx * 8) = v;
        }
    }
    // W(0) -> regs -> wsh[0]
    float4 wreg[4];
    #pragma unroll
    for (int i = 0; i < 4; ++i)
        wreg[i] = *reinterpret_cast<const float4*>(wB1 + (size_t)(tid + i * 512) * 8);
    #pragma unroll
    for (int i = 0; i < 4; ++i)
        *reinterpret_cast<float4*>(&wsh[0][(tid + i * 512) * 8]) = wreg[i];
    __syncthreads();

    const int lane = tid & 63;
    const int wid = tid >> 6;
    const int wr = wid & 1;            // px half (4 rows of 16)
    const int wc = wid >> 1;           // oc quarter (64 of 256)
    const int l15 = lane & 15, lh = lane >> 4;

    f32x4 acc[4][4];
    const f32x4 zero = {0.f, 0.f, 0.f, 0.f};
    #pragma unroll
    for (int ty = 0; ty < 4; ++ty)
        #pragma unroll
        for (int ot = 0; ot < 4; ++ot) acc[ty][ot] = zero;

    for (int tap = 0; tap < 9; ++tap) {
        const int cur = tap & 1;
        if (tap < 8) {
            #pragma unroll
            for (int i = 0; i < 4; ++i)
                wreg[i] = *reinterpret_cast<const float4*>(
                    wB1 + ((size_t)(tap + 1) * 16384 + (tid + i * 512) * 8));
        }
        const int r = tap / 3, s = tap - r * 3;
        const int j = l15 + s;                    // patch col
        #pragma unroll
        for (int h = 0; h < 2; ++h) {
            const int c = h * 4 + lh;             // cin group 0..7
            const int sl = c ^ (j & 7);
            f16x8 af[4], bf[4];
            #pragma unroll
            for (int ty = 0; ty < 4; ++ty) {
                int row = wr * 4 + ty + r;
                af[ty] = *reinterpret_cast<const f16x8*>(xs + (row * 18 + j) * 64 + sl * 8);
            }
            #pragma unroll
            for (int ot = 0; ot < 4; ++ot) {
                int oc = wc * 64 + ot * 16 + l15;
                int slw = c ^ (oc & 7);
                bf[ot] = *reinterpret_cast<const f16x8*>(&wsh[cur][oc * 64 + slw * 8]);
            }
            #pragma unroll
            for (int ty = 0; ty < 4; ++ty)
                #pragma unroll
                for (int ot = 0; ot < 4; ++ot)
                    acc[ty][ot] = __builtin_amdgcn_mfma_f32_16x16x32_f16(
                        af[ty], bf[ot], acc[ty][ot], 0, 0, 0);
        }
        if (tap < 8) {
            #pragma unroll
            for (int i = 0; i < 4; ++i)
                *reinterpret_cast<float4*>(&wsh[cur ^ 1][(tid + i * 512) * 8]) = wreg[i];
        }
        __syncthreads();
    }

    // epilogue -> offsT tile layout; D: col(oc)=l15, px-x = lh*4+reg
    #pragma unroll
    for (int ot = 0; ot < 4; ++ot) {
        int oc = wc * 64 + ot * 16 + l15;
        if (oc >= OCOFFc) continue;
        float bi = cob[oc];
        bool sig = (oc >= 144);
        int dg, k, comp;
        if (oc < 144) { dg = oc / 18; int rem = oc - dg * 18; k = rem >> 1; comp = rem & 1; }
        else          { int mm = oc - 144; dg = mm / 9; k = mm - dg * 9; comp = 2; }
        int tile = by * 16 + bx * 2 + (lh >> 1);
        __half* dstb = offsT + ((((size_t)(b * 256 + tile) * 8 + dg) * 9 + k) * 3 + comp) * 64
                       + (lh & 1) * 4;
        #pragma unroll
        for (int ty = 0; ty < 4; ++ty) {
            int y = wr * 4 + ty;                  // row within 8x8 tile
            float v0 = acc[ty][ot][0] + bi, v1 = acc[ty][ot][1] + bi;
            float v2 = acc[ty][ot][2] + bi, v3 = acc[ty][ot][3] + bi;
            if (sig) {
                v0 = 1.f / (1.f + __expf(-v0)); v1 = 1.f / (1.f + __expf(-v1));
                v2 = 1.f / (1.f + __expf(-v2)); v3 = 1.f / (1.f + __expf(-v3));
            }
            __half2* dst = reinterpret_cast<__half2*>(dstb + y * 8);
            dst[0] = __halves2half2(__float2half(v0), __float2half(v1));
            dst[1] = __halves2half2(__float2half(v2), __float2half(v3));
        }
    }
}

// ---------- K2: wave-per-dg sampling + MFMA, zero barriers in main loop ----------
// 512 thr = 8 waves; wave w owns dg=w end-to-end; 2-barrier LDS reduction at end
__global__ __launch_bounds__(512, 2) void dcn_main_k(
        const __half* __restrict__ offsT, const __half* __restrict__ xT,
        const __half* __restrict__ wM, const float* __restrict__ bias,
        float* __restrict__ out) {
    __shared__ __align__(16) float redbuf[8 * 64 * 64];   // 128 KB; col aliased on top
    __half* col = reinterpret_cast<__half*>(redbuf);      // per-wave [12kg][64px][8c]
    const int tid = threadIdx.x;
    const int tx = blockIdx.x, ty = blockIdx.y, b = blockIdx.z;
    const int lane = tid & 63, wid = tid >> 6;            // wid == dg
    const int l15 = lane & 15, lh = lane >> 4;

    // preload this wave's 12 B-fragments (kg = s*4+lh, oc = n*16+l15); in flight during sampling
    f16x8 bf[12];
    #pragma unroll
    for (int s = 0; s < 3; ++s)
        #pragma unroll
        for (int n = 0; n < 4; ++n)
            bf[s * 4 + n] = *reinterpret_cast<const f16x8*>(
                wM + (size_t)((wid * 12 + s * 4 + lh) * 64 + n * 16 + l15) * 8);

    // zero pad kgs 9..11 of own col region (768 = 12*64 sites per wave)
    {
        uint4 z = {0u, 0u, 0u, 0u};
        #pragma unroll
        for (int i = 0; i < 3; ++i)
            *reinterpret_cast<uint4*>(col + ((size_t)wid * 768 + (9 + i) * 64 + lane) * 8) = z;
    }

    // sampling: 9 taps x 64 px, wave-private, no barriers
    const __half* tb = offsT + (size_t)(b * 256 + ty * 16 + tx) * 8 * 9 * 3 * 64;
    const __half* xb = xT + (size_t)(b * 8 + wid) * XP * XP * 8;
    const int px = lane;
    const int gy = ty * 8 + (px >> 3), gx = tx * 8 + (px & 7);
    #pragma unroll 1
    for (int k = 0; k < 9; ++k) {
        const __half* op = tb + (wid * 9 + k) * 192;
        float oy = __half2float(op[px]);
        float ox = __half2float(op[64 + px]);
        float m  = __half2float(op[128 + px]);
        const int ki = k / 3, kj = k - ki * 3;
        float sy = oy + (float)(gy - 1 + ki);
        float sx = ox + (float)(gx - 1 + kj);
        float y0f = floorf(sy), x0f = floorf(sx);
        int iy0 = (int)y0f, ix0 = (int)x0f;
        float ly = sy - y0f, lx = sx - x0f;
        float hy = 1.f - ly, hx = 1.f - lx;
        float vy0 = ((unsigned)iy0 < 128u) ? 1.f : 0.f;
        float vy1 = ((unsigned)(iy0 + 1) < 128u) ? 1.f : 0.f;
        float vx0 = ((unsigned)ix0 < 128u) ? 1.f : 0.f;
        float vx1 = ((unsigned)(ix0 + 1) < 128u) ? 1.f : 0.f;
        float w00 = hy * hx * vy0 * vx0 * m, w01 = hy * lx * vy0 * vx1 * m;
        float w10 = ly * hx * vy1 * vx0 * m, w11 = ly * lx * vy1 * vx1 * m;
        int y0c = min(max(iy0, 0), 127), y1c = min(max(iy0 + 1, 0), 127);
        int x0c = min(max(ix0, 0), 127), x1c = min(max(ix0 + 1, 0), 127);
        float4 f00 = *reinterpret_cast<const float4*>(xb + ((size_t)(y0c + 1) * XP + x0c + 1) * 8);
        float4 f01 = *reinterpret_cast<const float4*>(xb + ((size_t)(y0c + 1) * XP + x1c + 1) * 8);
        float4 f10 = *reinterpret_cast<const float4*>(xb + ((size_t)(y1c + 1) * XP + x0c + 1) * 8);
        float4 f11 = *reinterpret_cast<const float4*>(xb + ((size_t)(y1c + 1) * XP + x1c + 1) * 8);
        const __half2* a00 = reinterpret_cast<const __half2*>(&f00);
        const __half2* a01 = reinterpret_cast<const __half2*>(&f01);
        const __half2* a10 = reinterpret_cast<const __half2*>(&f10);
        const __half2* a11 = reinterpret_cast<const __half2*>(&f11);
        __half2 W00 = __float2half2_rn(w00), W01 = __float2half2_rn(w01);
        __half2 W10 = __float2half2_rn(w10), W11 = __float2half2_rn(w11);
        __half2 rr[4];
        #pragma unroll
        for (int cc = 0; cc < 4; ++cc)
            rr[cc] = __hfma2(a00[cc], W00,
                     __hfma2(a01[cc], W01,
                     __hfma2(a10[cc], W10, __hmul2(a11[cc], W11))));
        *reinterpret_cast<uint4*>(col + ((size_t)wid * 768 + k * 64 + px) * 8) =
            *reinterpret_cast<const uint4*>(rr);
    }

    // MFMA: this wave's dg contribution to full 64px x 64oc tile, K=96
    f32x4 acc[4][4];
    const f32x4 zero = {0.f, 0.f, 0.f, 0.f};
    #pragma unroll
    for (int m = 0; m < 4; ++m)
        #pragma unroll
        for (int n = 0; n < 4; ++n) acc[m][n] = zero;
    #pragma unroll
    for (int s = 0; s < 3; ++s) {
        #pragma unroll
        for (int m = 0; m < 4; ++m) {
            f16x8 af = *reinterpret_cast<const f16x8*>(
                col + ((size_t)wid * 768 + (s * 4 + lh) * 64 + m * 16 + l15) * 8);
            #pragma unroll
            for (int n = 0; n < 4; ++n)
                acc[m][n] = __builtin_amdgcn_mfma_f32_16x16x32_f16(af, bf[s * 4 + n], acc[m][n], 0, 0, 0);
        }
    }

    __syncthreads();   // all col reads done; redbuf may be overwritten
    // partial[wid][px][oc] f32
    #pragma unroll
    for (int m = 0; m < 4; ++m)
        #pragma unroll
        for (int n = 0; n < 4; ++n)
            #pragma unroll
            for (int rg = 0; rg < 4; ++rg) {
                int ppx = m * 16 + lh * 4 + rg;
                int oc = n * 16 + l15;
                redbuf[wid * 4096 + ppx * 64 + oc] = acc[m][n][rg];
            }
    __syncthreads();

    // final: wave w sums spatial row w of the 8x8 tile; lane = oc
    const float bi = bias[lane];
    float vals[8];
    #pragma unroll
    for (int r = 0; r < 8; ++r) {
        int ppx = wid * 8 + r;
        float sacc = bi;
        #pragma unroll
        for (int p = 0; p < 8; ++p) sacc += redbuf[p * 4096 + ppx * 64 + lane];
        vals[r] = sacc;
    }
    float* obase = out + (size_t)(b * 64 + lane) * HWc + (ty * 8 + wid) * 128 + tx * 8;
    *reinterpret_cast<float4*>(obase)     = make_float4(vals[0], vals[1], vals[2], vals[3]);
    *reinterpret_cast<float4*>(obase + 4) = make_float4(vals[4], vals[5], vals[6], vals[7]);
}

extern "C" void kernel_launch(void* const* d_in, const int* in_sizes, int n_in,
                              void* d_out, int out_size, void* d_ws, size_t ws_size,
                              hipStream_t stream) {
    const float* x      = (const float*)d_in[0];
    const float* w_off  = (const float*)d_in[1];
    const float* cob    = (const float*)d_in[2];
    const float* weight = (const float*)d_in[3];
    const float* bias   = (const float*)d_in[4];
    float* out = (float*)d_out;
    if (ws_size < WS_NEEDED) return;

    char* ws = (char*)d_ws;
    __half* offsT = (__half*)ws;
    __half* xT    = (__half*)(ws + XT_OFF);
    __half* wB1   = (__half*)(ws + WB1_OFF);
    __half* wM    = (__half*)(ws + WM_OFF);

    prep_all<<<1825, 256, 0, stream>>>(x, w_off, weight, xT, wB1, wM);
    offset_mfma_k<<<dim3(8, 16, 2), 512, 0, stream>>>(xT, wB1, cob, offsT);
    dcn_main_k<<<dim3(16, 16, 2), 512, 0, stream>>>(offsT, xT, wM, bias, out);
}

// Round 6
// 51.341 us; speedup vs baseline: 4.9419x; 1.0079x over previous
//
#include <hip/hip_runtime.h>
#include <hip/hip_fp16.h>

// DCNv2: B=2, CIN=COUT=64, H=W=128, DG=8, cpg=8, 3x3 s1 p1 d1
constexpr int BB = 2;
constexpr int CINc = 64;
constexpr int HWc = 128 * 128;
constexpr int OCOFFc = 216;   // DG*3*9 offset-conv channels
constexpr int XP = 130;       // padded spatial dim (halo of 1)

// workspace layout (bytes)
constexpr size_t XT_BYTES  = (size_t)BB * 8 * XP * XP * 8 * 2;   // per-(b,dg) planes, 16B/px
constexpr size_t WB1_OFF   = XT_BYTES;
constexpr size_t WB1_BYTES = (size_t)9 * 256 * 64 * 2;           // offset W [tap][oc256][sl][8] fp16
constexpr size_t WM_OFF    = WB1_OFF + WB1_BYTES;
constexpr size_t WM_BYTES  = (size_t)8 * 12 * 64 * 8 * 2;        // main W [dg][tap12][oc][8c] fp16
constexpr size_t WS_NEEDED = WM_OFF + WM_BYTES;                  // ~4.7 MB

typedef _Float16 f16x8 __attribute__((ext_vector_type(8)));
typedef float    f32x4 __attribute__((ext_vector_type(4)));

// ---------- K0: fused prep: x->planes, weight transforms, halo zero ----------
__global__ void prep_all(const float* __restrict__ x, const float* __restrict__ w_off,
                         const float* __restrict__ weight,
                         __half* __restrict__ xT, __half* __restrict__ wB1,
                         __half* __restrict__ wM) {
    int bid = blockIdx.x;
    if (bid < 1024) {
        int site = bid * 256 + threadIdx.x;      // B*8*HW = 262144
        int pix = site & (HWc - 1);
        int bdg = site >> 14;
        int dg = bdg & 7, b = bdg >> 3;
        int y = pix >> 7, xc = pix & 127;
        const float* xp = x + (size_t)(b * CINc + dg * 8) * HWc + pix;
        __half2 h0 = __halves2half2(__float2half(xp[0 * HWc]), __float2half(xp[1 * HWc]));
        __half2 h1 = __halves2half2(__float2half(xp[2 * HWc]), __float2half(xp[3 * HWc]));
        __half2 h2 = __halves2half2(__float2half(xp[4 * HWc]), __float2half(xp[5 * HWc]));
        __half2 h3 = __halves2half2(__float2half(xp[6 * HWc]), __float2half(xp[7 * HWc]));
        __half2* o = reinterpret_cast<__half2*>(
            xT + (((size_t)(b * 8 + dg) * XP + y + 1) * XP + xc + 1) * 8);
        o[0] = h0; o[1] = h1; o[2] = h2; o[3] = h3;
        return;
    }
    int idx = (bid - 1024) * 256 + threadIdx.x;
    if (idx < 9 * 256 * 64) {
        // wB1[tap][oc][sl][ci], slot sl holds cin-group sl^(oc&7)
        int ci = idx & 7;
        int sl = (idx >> 3) & 7;
        int oc = (idx >> 6) & 255;
        int tap = idx >> 14;
        int cin = ((sl ^ (oc & 7)) << 3) + ci;
        float v = (oc < OCOFFc) ? w_off[oc * 576 + cin * 9 + tap] : 0.f;
        wB1[idx] = __float2half(v);
    } else if (idx < 9 * 256 * 64 + 8 * 12 * 64 * 8) {
        int j = idx - 9 * 256 * 64;          // wM[dg][tap12][oc][c]
        int c = j & 7;
        int oc = (j >> 3) & 63;
        int tg = j >> 9;                      // dg*12 + tap
        int tap = tg % 12;
        int dg = tg / 12;
        float v = (tap < 9) ? weight[oc * 576 + (dg * 8 + c) * 9 + tap] : 0.f;
        wM[j] = __float2half(v);
    } else {
        int j2 = idx - (9 * 256 * 64 + 8 * 12 * 64 * 8);   // halo zero: 16 planes x 516 px
        if (j2 < 16 * 516) {
            int plane = j2 / 516;
            int p = j2 - plane * 516;
            int y, xx;
            if (p < 130)      { y = 0;           xx = p; }
            else if (p < 260) { y = 129;         xx = p - 130; }
            else if (p < 388) { y = 1 + p - 260; xx = 0; }
            else              { y = 1 + p - 388; xx = 129; }
            uint4 z = {0u, 0u, 0u, 0u};
            *reinterpret_cast<uint4*>(xT + (((size_t)plane * XP + y) * XP + xx) * 8) = z;
        }
    }
}

// ---------- Fused: offset conv (MFMA) -> LDS offsets -> sampling -> main conv (MFMA) ----
// grid (8,16,2) = 256 blocks, 512 thr = 8 waves; tile 16x8 px.
// Phase A: 128px x 256oc implicit GEMM (waves: 2 px-halves x 4 oc-quarters).
// Main: wave w owns image row w (16px); per dg samples af fragments directly
//       into registers (no col LDS, no reduction, no barriers).
__global__ __launch_bounds__(512, 2) void dcn_fused_k(
        const __half* __restrict__ xT, const __half* __restrict__ wB1,
        const float* __restrict__ cob, const __half* __restrict__ wM,
        const float* __restrict__ bias, float* __restrict__ out) {
    __shared__ __half xs[1440 * 8];       // 23040 B: [row10][col18][sl8][8ch]
    __shared__ __half wsh[2][2048 * 8];   // 65536 B: [oc256][sl8][8ch] double-buffered
    __shared__ __half offsb[216 * 132];   // 57024 B: [(dg*9+k)*3+comp][px128 pad132]
    const int tid = threadIdx.x;
    const int bx = blockIdx.x;            // 0..7   (16 px wide)
    const int by = blockIdx.y;            // 0..15  (8 px tall)
    const int b  = blockIdx.z;

    // ---- Phase A staging: x patch (rows by*8..+9, cols bx*16..+17), XOR slot swizzle ----
    #pragma unroll
    for (int it = 0; it < 3; ++it) {
        int idx = tid + it * 512;
        if (idx < 1440) {
            int yl = idx / 144;                  // 144 = 18 cols * 8 slots
            int rem = idx - yl * 144;
            int cl = rem >> 3, sl = rem & 7;
            int dg = sl ^ (cl & 7);
            float4 v = *reinterpret_cast<const float4*>(
                xT + (((size_t)(b * 8 + dg) * XP + by * 8 + yl) * XP + bx * 16 + cl) * 8);
            *reinterpret_cast<float4*>(xs + idx * 8) = v;
        }
    }
    // W(0) -> regs -> wsh[0]
    float4 wreg[4];
    #pragma unroll
    for (int i = 0; i < 4; ++i)
        wreg[i] = *reinterpret_cast<const float4*>(wB1 + (size_t)(tid + i * 512) * 8);
    #pragma unroll
    for (int i = 0; i < 4; ++i)
        *reinterpret_cast<float4*>(&wsh[0][(tid + i * 512) * 8]) = wreg[i];
    __syncthreads();

    const int lane = tid & 63;
    const int wid = tid >> 6;
    const int wr = wid & 1;            // px half (4 image rows)
    const int wc = wid >> 1;           // oc quarter (64 of 256)
    const int l15 = lane & 15, lh = lane >> 4;

    {
        f32x4 acc[4][4];
        const f32x4 zero = {0.f, 0.f, 0.f, 0.f};
        #pragma unroll
        for (int ty = 0; ty < 4; ++ty)
            #pragma unroll
            for (int ot = 0; ot < 4; ++ot) acc[ty][ot] = zero;

        #pragma unroll 1
        for (int tap = 0; tap < 9; ++tap) {
            const int cur = tap & 1;
            if (tap < 8) {
                #pragma unroll
                for (int i = 0; i < 4; ++i)
                    wreg[i] = *reinterpret_cast<const float4*>(
                        wB1 + ((size_t)(tap + 1) * 16384 + (tid + i * 512) * 8));
            }
            const int r = tap / 3, s = tap - r * 3;
            const int j = l15 + s;                    // patch col
            #pragma unroll
            for (int h = 0; h < 2; ++h) {
                const int c = h * 4 + lh;             // cin group 0..7
                const int sl = c ^ (j & 7);
                f16x8 af[4], bf[4];
                #pragma unroll
                for (int ty = 0; ty < 4; ++ty) {
                    int row = wr * 4 + ty + r;
                    af[ty] = *reinterpret_cast<const f16x8*>(xs + (row * 18 + j) * 64 + sl * 8);
                }
                #pragma unroll
                for (int ot = 0; ot < 4; ++ot) {
                    int oc = wc * 64 + ot * 16 + l15;
                    int slw = c ^ (oc & 7);
                    bf[ot] = *reinterpret_cast<const f16x8*>(&wsh[cur][oc * 64 + slw * 8]);
                }
                #pragma unroll
                for (int ty = 0; ty < 4; ++ty)
                    #pragma unroll
                    for (int ot = 0; ot < 4; ++ot)
                        acc[ty][ot] = __builtin_amdgcn_mfma_f32_16x16x32_f16(
                            af[ty], bf[ot], acc[ty][ot], 0, 0, 0);
            }
            if (tap < 8) {
                #pragma unroll
                for (int i = 0; i < 4; ++i)
                    *reinterpret_cast<float4*>(&wsh[cur ^ 1][(tid + i * 512) * 8]) = wreg[i];
            }
            __syncthreads();
        }

        // ---- Phase A epilogue -> offsb (LDS). D: oc=l15-col, x-offset=lh*4+reg ----
        #pragma unroll
        for (int ot = 0; ot < 4; ++ot) {
            int oc = wc * 64 + ot * 16 + l15;
            if (oc < OCOFFc) {
                float bi = cob[oc];
                bool sig = (oc >= 144);
                int dg, k, comp;
                if (oc < 144) { dg = oc / 18; int rem = oc - dg * 18; k = rem >> 1; comp = rem & 1; }
                else          { int mm = oc - 144; dg = mm / 9; k = mm - dg * 9; comp = 2; }
                int r3 = (dg * 9 + k) * 3 + comp;
                #pragma unroll
                for (int ty = 0; ty < 4; ++ty) {
                    int px = (wr * 4 + ty) * 16 + lh * 4;
                    float v0 = acc[ty][ot][0] + bi, v1 = acc[ty][ot][1] + bi;
                    float v2 = acc[ty][ot][2] + bi, v3 = acc[ty][ot][3] + bi;
                    if (sig) {
                        v0 = 1.f / (1.f + __expf(-v0)); v1 = 1.f / (1.f + __expf(-v1));
                        v2 = 1.f / (1.f + __expf(-v2)); v3 = 1.f / (1.f + __expf(-v3));
                    }
                    __half2* d = reinterpret_cast<__half2*>(&offsb[r3 * 132 + px]);
                    d[0] = __halves2half2(__float2half(v0), __float2half(v1));
                    d[1] = __halves2half2(__float2half(v2), __float2half(v3));
                }
            }
        }
    }
    __syncthreads();   // offsb complete

    // ---- Main conv: wave wid owns image row wid of the 16x8 tile ----
    const int gy = by * 8 + wid;
    const int gxb = bx * 16;
    float bias_r[4];
    #pragma unroll
    for (int n = 0; n < 4; ++n) bias_r[n] = bias[n * 16 + l15];

    f32x4 acc2[4];
    const f32x4 zero2 = {0.f, 0.f, 0.f, 0.f};
    #pragma unroll
    for (int n = 0; n < 4; ++n) acc2[n] = zero2;

    const int px = wid * 16 + l15;    // index into offsb rows
    const int gx = gxb + l15;

    #pragma unroll 1
    for (int dg = 0; dg < 8; ++dg) {
        // B fragments for this dg (12 = 3 K-steps x 4 oc-frags); issue before sampling
        f16x8 bf[12];
        #pragma unroll
        for (int s = 0; s < 3; ++s)
            #pragma unroll
            for (int n = 0; n < 4; ++n)
                bf[s * 4 + n] = *reinterpret_cast<const f16x8*>(
                    wM + (size_t)((dg * 12 + s * 4 + lh) * 64 + n * 16 + l15) * 8);
        const __half* xb = xT + (size_t)(b * 8 + dg) * XP * XP * 8;

        #pragma unroll
        for (int s = 0; s < 3; ++s) {
            const int kg = s * 4 + lh;        // tap index this lane supplies
            f16x8 af = {0, 0, 0, 0, 0, 0, 0, 0};
            if (kg < 9) {
                const int r3 = (dg * 9 + kg) * 3;
                float oy = __half2float(offsb[r3 * 132 + px]);
                float ox = __half2float(offsb[(r3 + 1) * 132 + px]);
                float m  = __half2float(offsb[(r3 + 2) * 132 + px]);
                const int ki = kg / 3, kj = kg - ki * 3;
                float sy = oy + (float)(gy - 1 + ki);
                float sx = ox + (float)(gx - 1 + kj);
                float y0f = floorf(sy), x0f = floorf(sx);
                int iy0 = (int)y0f, ix0 = (int)x0f;
                float ly = sy - y0f, lx = sx - x0f;
                float hy = 1.f - ly, hx = 1.f - lx;
                float vy0 = ((unsigned)iy0 < 128u) ? 1.f : 0.f;
                float vy1 = ((unsigned)(iy0 + 1) < 128u) ? 1.f : 0.f;
                float vx0 = ((unsigned)ix0 < 128u) ? 1.f : 0.f;
                float vx1 = ((unsigned)(ix0 + 1) < 128u) ? 1.f : 0.f;
                float w00 = hy * hx * vy0 * vx0 * m, w01 = hy * lx * vy0 * vx1 * m;
                float w10 = ly * hx * vy1 * vx0 * m, w11 = ly * lx * vy1 * vx1 * m;
                int y0c = min(max(iy0, 0), 127), y1c = min(max(iy0 + 1, 0), 127);
                int x0c = min(max(ix0, 0), 127), x1c = min(max(ix0 + 1, 0), 127);
                float4 f00 = *reinterpret_cast<const float4*>(xb + ((size_t)(y0c + 1) * XP + x0c + 1) * 8);
                float4 f01 = *reinterpret_cast<const float4*>(xb + ((size_t)(y0c + 1) * XP + x1c + 1) * 8);
                float4 f10 = *reinterpret_cast<const float4*>(xb + ((size_t)(y1c + 1) * XP + x0c + 1) * 8);
                float4 f11 = *reinterpret_cast<const float4*>(xb + ((size_t)(y1c + 1) * XP + x1c + 1) * 8);
                const __half2* a00 = reinterpret_cast<const __half2*>(&f00);
                const __half2* a01 = reinterpret_cast<const __half2*>(&f01);
                const __half2* a10 = reinterpret_cast<const __half2*>(&f10);
                const __half2* a11 = reinterpret_cast<const __half2*>(&f11);
                __half2 W00 = __float2half2_rn(w00), W01 = __float2half2_rn(w01);
                __half2 W10 = __float2half2_rn(w10), W11 = __float2half2_rn(w11);
                __align__(16) __half2 rr[4];
                #pragma unroll
                for (int cc = 0; cc < 4; ++cc)
                    rr[cc] = __hfma2(a00[cc], W00,
                             __hfma2(a01[cc], W01,
                             __hfma2(a10[cc], W10, __hmul2(a11[cc], W11))));
                af = *reinterpret_cast<const f16x8*>(rr);
            }
            #pragma unroll
            for (int n = 0; n < 4; ++n)
                acc2[n] = __builtin_amdgcn_mfma_f32_16x16x32_f16(af, bf[s * 4 + n], acc2[n], 0, 0, 0);
        }
    }

    // ---- store: D row = x-offset (lh*4+reg), col = oc (n*16+l15) ----
    #pragma unroll
    for (int n = 0; n < 4; ++n) {
        int oc = n * 16 + l15;
        float bi = bias_r[n];
        float4 v = make_float4(acc2[n][0] + bi, acc2[n][1] + bi,
                               acc2[n][2] + bi, acc2[n][3] + bi);
        *reinterpret_cast<float4*>(
            out + (size_t)(b * 64 + oc) * HWc + gy * 128 + gxb + lh * 4) = v;
    }
}

extern "C" void kernel_launch(void* const* d_in, const int* in_sizes, int n_in,
                              void* d_out, int out_size, void* d_ws, size_t ws_size,
                              hipStream_t stream) {
    const float* x      = (const float*)d_in[0];
    const float* w_off  = (const float*)d_in[1];
    const float* cob    = (const float*)d_in[2];
    const float* weight = (const float*)d_in[3];
    const float* bias   = (const float*)d_in[4];
    float* out = (float*)d_out;
    if (ws_size < WS_NEEDED) return;

    char* ws = (char*)d_ws;
    __half* xT  = (__half*)ws;
    __half* wB1 = (__half*)(ws + WB1_OFF);
    __half* wM  = (__half*)(ws + WM_OFF);

    prep_all<<<1825, 256, 0, stream>>>(x, w_off, weight, xT, wB1, wM);
    dcn_fused_k<<<dim3(8, 16, 2), 512, 0, stream>>>(xT, wB1, cob, wM, bias, out);
}